// Round 1
// baseline (1246.800 us; speedup 1.0000x reference)
//
#include <hip/hip_runtime.h>
#include <hip/hip_bf16.h>
#include <stdint.h>

#define LN_EPS 1e-5f

typedef __hip_bfloat16 bf16;
typedef short short8 __attribute__((ext_vector_type(8)));
typedef float f32x4 __attribute__((ext_vector_type(4)));

static __device__ __forceinline__ float bf2f(short s) {
    unsigned int u = ((unsigned int)(unsigned short)s) << 16;
    return __uint_as_float(u);
}
static __device__ __forceinline__ short f2bf(float x) {
    __hip_bfloat16 h = __float2bfloat16(x);
    return *reinterpret_cast<short*>(&h);
}

// ---------------- weight transpose + bf16 convert ----------------
struct TDesc { const float* src; bf16* dst; int K; int N; int kOff; };
struct TDescs { TDesc d[9]; };

__global__ void transpose_all_kernel(TDescs descs) {
    TDesc t = descs.d[blockIdx.z];
    int kb = blockIdx.x * 32, nb = blockIdx.y * 32;
    if (kb >= t.K || nb >= t.N) return;
    __shared__ float tile[32][33];
    int tx = threadIdx.x & 31, ty = threadIdx.x >> 5;  // 256 thr: ty 0..7
    for (int i = ty; i < 32; i += 8) {
        int k = kb + i, n = nb + tx;
        tile[i][tx] = (k < t.K && n < t.N) ? t.src[(size_t)(t.kOff + k) * t.N + n] : 0.f;
    }
    __syncthreads();
    for (int i = ty; i < 32; i += 8) {
        int n = nb + i, k = kb + tx;
        if (n < t.N && k < t.K)
            t.dst[(size_t)n * t.K + k] = __float2bfloat16(tile[tx][i]);
    }
}

// ---------------- f32 -> bf16 convert ----------------
__global__ void cvt_bf16_kernel(const float* __restrict__ src, bf16* __restrict__ dst, int n) {
    int i = blockIdx.x * 256 + threadIdx.x;
    int idx = i * 4;
    if (idx >= n) return;
    float4 v = *(const float4*)(src + idx);
    dst[idx + 0] = __float2bfloat16(v.x);
    dst[idx + 1] = __float2bfloat16(v.y);
    dst[idx + 2] = __float2bfloat16(v.z);
    dst[idx + 3] = __float2bfloat16(v.w);
}

// ---------------- edge MLP layer 1 (K=4, fp32) ----------------
__global__ void edge_l1_kernel(const float* __restrict__ attr, const float* __restrict__ w1,
                               const float* __restrict__ b1, bf16* __restrict__ h1, int E) {
    int idx = blockIdx.x * 256 + threadIdx.x;
    if (idx >= E * 512) return;
    int e = idx >> 9, d = idx & 511;
    float4 a = *(const float4*)(attr + (size_t)e * 4);
    float s = a.x * w1[d] + a.y * w1[512 + d] + a.z * w1[1024 + d] + a.w * w1[1536 + d] + b1[d];
    h1[idx] = __float2bfloat16(fmaxf(s, 0.f));
}

// ---------------- generic bf16 MFMA GEMM: C[M,N] = A[M,K] * BT[N,K]^T ----------------
// EPI: 0 = none, 1 = +bias, 2 = +bias, relu.  Output bf16.
template <int EPI>
__global__ __launch_bounds__(256, 2) void gemm_bt_kernel(
    const bf16* __restrict__ A, const bf16* __restrict__ BT,
    const float* __restrict__ bias, bf16* __restrict__ C, int M, int N, int K) {
    __shared__ short As[128][72];
    __shared__ short Bs[128][72];
    const int t = threadIdx.x;
    const int lane = t & 63, w = t >> 6;
    const int wm = w >> 1, wn = w & 1;
    const int lr = lane & 15, lh = lane >> 4;
    const int row0 = blockIdx.y * 128;
    const int col0 = blockIdx.x * 128;

    f32x4 acc[4][4];
#pragma unroll
    for (int i = 0; i < 4; i++)
#pragma unroll
        for (int j = 0; j < 4; j++) acc[i][j] = {0.f, 0.f, 0.f, 0.f};

    for (int k0 = 0; k0 < K; k0 += 64) {
#pragma unroll
        for (int i = 0; i < 4; i++) {
            int q = i * 256 + t;
            int r = q >> 3, ck = q & 7;
            int grow = row0 + r;
            short8 av = {0, 0, 0, 0, 0, 0, 0, 0};
            if (grow < M) av = *(const short8*)(A + (size_t)grow * K + k0 + ck * 8);
            *(short8*)&As[r][ck * 8] = av;
            int gn = col0 + r;
            short8 bv = {0, 0, 0, 0, 0, 0, 0, 0};
            if (gn < N) bv = *(const short8*)(BT + (size_t)gn * K + k0 + ck * 8);
            *(short8*)&Bs[r][ck * 8] = bv;
        }
        __syncthreads();
#pragma unroll
        for (int kk = 0; kk < 64; kk += 32) {
            short8 af[4], bfv[4];
#pragma unroll
            for (int mf = 0; mf < 4; mf++)
                af[mf] = *(const short8*)&As[wm * 64 + mf * 16 + lr][kk + lh * 8];
#pragma unroll
            for (int nf = 0; nf < 4; nf++)
                bfv[nf] = *(const short8*)&Bs[wn * 64 + nf * 16 + lr][kk + lh * 8];
#pragma unroll
            for (int mf = 0; mf < 4; mf++)
#pragma unroll
                for (int nf = 0; nf < 4; nf++)
                    acc[mf][nf] = __builtin_amdgcn_mfma_f32_16x16x32_bf16(
                        af[mf], bfv[nf], acc[mf][nf], 0, 0, 0);
        }
        __syncthreads();
    }

#pragma unroll
    for (int nf = 0; nf < 4; nf++) {
        int col = col0 + wn * 64 + nf * 16 + lr;
        float bv = (EPI >= 1) ? bias[col] : 0.f;
#pragma unroll
        for (int mf = 0; mf < 4; mf++) {
#pragma unroll
            for (int r = 0; r < 4; r++) {
                int row = row0 + wm * 64 + mf * 16 + lh * 4 + r;
                if (row < M) {
                    float v = acc[mf][nf][r] + bv;
                    if (EPI == 2) v = fmaxf(v, 0.f);
                    C[(size_t)row * N + col] = __float2bfloat16(v);
                }
            }
        }
    }
}

// ---------------- per-edge combine: H2 = relu(T3 + grid_proj[recv] + mesh_proj[send] + b1) ----------------
__global__ void edge_combine_kernel(bf16* __restrict__ T3, const bf16* __restrict__ gridp,
                                    const bf16* __restrict__ meshp, const float* __restrict__ b1,
                                    const int* __restrict__ send, const int* __restrict__ recv, int E) {
    int idx = blockIdx.x * 256 + threadIdx.x;  // one per 8 elems
    if (idx >= E * 64) return;
    int e = idx >> 6;
    int d0 = (idx & 63) * 8;
    int sn = send[e], rn = recv[e];
    short8 tv = *(const short8*)(T3 + (size_t)e * 512 + d0);
    short8 gp = *(const short8*)(gridp + (size_t)rn * 512 + d0);
    short8 mp = *(const short8*)(meshp + (size_t)sn * 512 + d0);
    float4 bA = *(const float4*)(b1 + d0);
    float4 bB = *(const float4*)(b1 + d0 + 4);
    float bb[8] = {bA.x, bA.y, bA.z, bA.w, bB.x, bB.y, bB.z, bB.w};
    short8 o;
#pragma unroll
    for (int j = 0; j < 8; j++)
        o[j] = f2bf(fmaxf(bf2f(tv[j]) + bf2f(gp[j]) + bf2f(mp[j]) + bb[j], 0.f));
    *(short8*)(T3 + (size_t)e * 512 + d0) = o;
}

// ---------------- LayerNorm family: one wave per row ----------------
// MODE 0: out bf16 = LN(x)*g+b           (DN=512)
// MODE 1: atomicAdd aggr[recv[row]] += LN(x)*g+b  (DN=512)
// MODE 2: out bf16 = resid_f32 + LN(x)*g+b (DN=512)
// MODE 3: out f32 = LN(x)*g+b            (DN=128)
template <int MODE, int DN>
__global__ void ln_kernel(const bf16* __restrict__ X, const float* __restrict__ gw,
                          const float* __restrict__ bw, bf16* __restrict__ outb,
                          float* __restrict__ outf, const float* __restrict__ resid,
                          const int* __restrict__ recv, float* __restrict__ aggr, int R) {
    constexpr int EPL = DN / 64;
    int row = blockIdx.x * 4 + (threadIdx.x >> 6);
    if (row >= R) return;
    int lane = threadIdx.x & 63;
    const bf16* xr = X + (size_t)row * DN + lane * EPL;
    float v[EPL];
    if constexpr (EPL == 8) {
        short8 t8 = *(const short8*)xr;
#pragma unroll
        for (int j = 0; j < 8; j++) v[j] = bf2f(t8[j]);
    } else {
#pragma unroll
        for (int j = 0; j < EPL; j++) v[j] = __bfloat162float(xr[j]);
    }
    float s = 0.f, s2 = 0.f;
#pragma unroll
    for (int j = 0; j < EPL; j++) { s += v[j]; s2 += v[j] * v[j]; }
#pragma unroll
    for (int o = 32; o > 0; o >>= 1) {
        s += __shfl_xor(s, o, 64);
        s2 += __shfl_xor(s2, o, 64);
    }
    float mu = s * (1.f / DN);
    float var = s2 * (1.f / DN) - mu * mu;
    float rs = rsqrtf(var + LN_EPS);
    int d0 = lane * EPL;

    if constexpr (MODE == 1) {
        int rnode = recv[row];
        float* ap = aggr + (size_t)rnode * DN + d0;
#pragma unroll
        for (int j = 0; j < EPL; j++) {
            float y = (v[j] - mu) * rs * gw[d0 + j] + bw[d0 + j];
            atomicAdd(ap + j, y);
        }
    } else if constexpr (MODE == 0) {
        short8 o;
#pragma unroll
        for (int j = 0; j < EPL; j++) {
            float y = (v[j] - mu) * rs * gw[d0 + j] + bw[d0 + j];
            o[j] = f2bf(y);
        }
        *(short8*)(outb + (size_t)row * DN + d0) = o;
    } else if constexpr (MODE == 2) {
        short8 o;
#pragma unroll
        for (int j = 0; j < EPL; j++) {
            float y = (v[j] - mu) * rs * gw[d0 + j] + bw[d0 + j];
            o[j] = f2bf(resid[(size_t)row * DN + d0 + j] + y);
        }
        *(short8*)(outb + (size_t)row * DN + d0) = o;
    } else {
#pragma unroll
        for (int j = 0; j < EPL; j++) {
            float y = (v[j] - mu) * rs * gw[d0 + j] + bw[d0 + j];
            outf[(size_t)row * DN + d0 + j] = y;
        }
    }
}

// ---------------- X2 = cat(grid_bf, bf16(aggr)) ----------------
__global__ void build_x2_kernel(const bf16* __restrict__ gridb, const float* __restrict__ aggr,
                                bf16* __restrict__ X2, int G) {
    int idx = blockIdx.x * 256 + threadIdx.x;  // one per 8 elems
    if (idx >= G * 128) return;
    int row = idx >> 7;
    int d0 = (idx & 127) * 8;
    bf16* dst = X2 + (size_t)row * 1024 + d0;
    if (d0 < 512) {
        *(short8*)dst = *(const short8*)(gridb + (size_t)row * 512 + d0);
    } else {
        const float* sp = aggr + (size_t)row * 512 + (d0 - 512);
        float4 a = *(const float4*)sp;
        float4 b = *(const float4*)(sp + 4);
        short8 o = {f2bf(a.x), f2bf(a.y), f2bf(a.z), f2bf(a.w),
                    f2bf(b.x), f2bf(b.y), f2bf(b.z), f2bf(b.w)};
        *(short8*)dst = o;
    }
}

extern "C" void kernel_launch(void* const* d_in, const int* in_sizes, int n_in,
                              void* d_out, int out_size, void* d_ws, size_t ws_size,
                              hipStream_t stream) {
    const int NM = 2562, NG = 16384, NE = 49152;
    const float* mesh   = (const float*)d_in[0];
    const float* grid   = (const float*)d_in[1];
    const float* attr   = (const float*)d_in[2];
    const int*   eidx   = (const int*)d_in[3];
    const int*   send   = eidx;        // mesh senders
    const int*   recv   = eidx + NE;   // grid receivers
    const float* emlp_w1 = (const float*)d_in[4];
    const float* emlp_b1 = (const float*)d_in[5];
    const float* emlp_w2 = (const float*)d_in[6];
    const float* emlp_b2 = (const float*)d_in[7];
    const float* emlp_g  = (const float*)d_in[8];
    const float* emlp_be = (const float*)d_in[9];
    const float* ge_w1 = (const float*)d_in[10];
    const float* ge_b1 = (const float*)d_in[11];
    const float* ge_w2 = (const float*)d_in[12];
    const float* ge_b2 = (const float*)d_in[13];
    const float* ge_g  = (const float*)d_in[14];
    const float* ge_be = (const float*)d_in[15];
    const float* gn_w1 = (const float*)d_in[16];
    const float* gn_b1 = (const float*)d_in[17];
    const float* gn_w2 = (const float*)d_in[18];
    const float* gn_b2 = (const float*)d_in[19];
    const float* gn_g  = (const float*)d_in[20];
    const float* gn_be = (const float*)d_in[21];
    const float* fin_w1 = (const float*)d_in[22];
    const float* fin_b1 = (const float*)d_in[23];
    const float* fin_w2 = (const float*)d_in[24];
    const float* fin_b2 = (const float*)d_in[25];
    const float* fin_g  = (const float*)d_in[26];
    const float* fin_be = (const float*)d_in[27];

    char* p = (char*)d_ws;
    auto take = [&](size_t bytes) -> char* {
        char* r = p;
        p += (bytes + 255) & ~(size_t)255;
        return r;
    };
    bf16* emlp_w2T = (bf16*)take((size_t)512 * 512 * 2);
    bf16* geA_T    = (bf16*)take((size_t)512 * 512 * 2);
    bf16* geB_T    = (bf16*)take((size_t)512 * 512 * 2);
    bf16* geC_T    = (bf16*)take((size_t)512 * 512 * 2);
    bf16* ge_w2T   = (bf16*)take((size_t)512 * 512 * 2);
    bf16* gn_w1T   = (bf16*)take((size_t)512 * 1024 * 2);
    bf16* gn_w2T   = (bf16*)take((size_t)512 * 512 * 2);
    bf16* fin_w1T  = (bf16*)take((size_t)512 * 512 * 2);
    bf16* fin_w2T  = (bf16*)take((size_t)128 * 512 * 2);
    bf16* grid_bf  = (bf16*)take((size_t)NG * 512 * 2);
    bf16* mesh_bf  = (bf16*)take((size_t)NM * 512 * 2);
    bf16* bufA     = (bf16*)take((size_t)NE * 512 * 2);  // H1 -> T3/H2 -> X2 -> latent
    bf16* bufB     = (bf16*)take((size_t)NE * 512 * 2);  // T2/edges_emb -> T5 -> T8 -> T11
    bf16* bufC     = (bf16*)take((size_t)NG * 512 * 2);  // grid_proj -> H3 -> H4
    bf16* bufD     = (bf16*)take((size_t)NM * 512 * 2);  // mesh_proj
    float* aggr    = (float*)take((size_t)NG * 512 * 4);

    // 1) transpose + bf16-convert all GEMM weights
    TDescs td;
    td.d[0] = {emlp_w2, emlp_w2T, 512, 512, 0};
    td.d[1] = {ge_w1,   geA_T,    512, 512, 0};
    td.d[2] = {ge_w1,   geB_T,    512, 512, 512};
    td.d[3] = {ge_w1,   geC_T,    512, 512, 1024};
    td.d[4] = {ge_w2,   ge_w2T,   512, 512, 0};
    td.d[5] = {gn_w1,   gn_w1T,  1024, 512, 0};
    td.d[6] = {gn_w2,   gn_w2T,   512, 512, 0};
    td.d[7] = {fin_w1,  fin_w1T,  512, 512, 0};
    td.d[8] = {fin_w2,  fin_w2T,  512, 128, 0};
    hipLaunchKernelGGL(transpose_all_kernel, dim3(32, 16, 9), dim3(256), 0, stream, td);

    // 2) bf16 inputs
    hipLaunchKernelGGL(cvt_bf16_kernel, dim3((NG * 512 / 4 + 255) / 256), dim3(256), 0, stream,
                       grid, grid_bf, NG * 512);
    hipLaunchKernelGGL(cvt_bf16_kernel, dim3((NM * 512 / 4 + 255) / 256), dim3(256), 0, stream,
                       mesh, mesh_bf, NM * 512);

    // zero aggregation buffer (poisoned by harness; atomics accumulate)
    hipMemsetAsync(aggr, 0, (size_t)NG * 512 * 4, stream);

    // 3) edge MLP layer1: H1 = relu(attr @ emlp_w1 + b1)  -> bufA
    hipLaunchKernelGGL(edge_l1_kernel, dim3(NE * 512 / 256), dim3(256), 0, stream,
                       attr, emlp_w1, emlp_b1, bufA, NE);

    // 4) T2 = H1 @ emlp_w2 + b2 -> bufB
    hipLaunchKernelGGL(gemm_bt_kernel<1>, dim3(4, NE / 128), dim3(256), 0, stream,
                       bufA, emlp_w2T, emlp_b2, bufB, NE, 512, 512);
    // 5) edges_emb = LN(T2)*g+b (in place, bufB)
    hipLaunchKernelGGL((ln_kernel<0, 512>), dim3(NE / 4), dim3(256), 0, stream,
                       bufB, emlp_g, emlp_be, bufB, (float*)nullptr, (const float*)nullptr,
                       (const int*)nullptr, (float*)nullptr, NE);

    // 6) grid_proj = grid_bf @ ge_w1[0:512] -> bufC
    hipLaunchKernelGGL(gemm_bt_kernel<0>, dim3(4, NG / 128), dim3(256), 0, stream,
                       grid_bf, geA_T, (const float*)nullptr, bufC, NG, 512, 512);
    // 7) mesh_proj = mesh_bf @ ge_w1[512:1024] -> bufD
    hipLaunchKernelGGL(gemm_bt_kernel<0>, dim3(4, (NM + 127) / 128), dim3(256), 0, stream,
                       mesh_bf, geB_T, (const float*)nullptr, bufD, NM, 512, 512);
    // 8) T3 = edges_emb @ ge_w1[1024:1536] -> bufA
    hipLaunchKernelGGL(gemm_bt_kernel<0>, dim3(4, NE / 128), dim3(256), 0, stream,
                       bufB, geC_T, (const float*)nullptr, bufA, NE, 512, 512);
    // 9) H2 = relu(T3 + grid_proj[recv] + mesh_proj[send] + ge_b1)  (in place, bufA)
    hipLaunchKernelGGL(edge_combine_kernel, dim3(NE * 64 / 256), dim3(256), 0, stream,
                       bufA, bufC, bufD, ge_b1, send, recv, NE);
    // 10) T5 = H2 @ ge_w2 + b2 -> bufB
    hipLaunchKernelGGL(gemm_bt_kernel<1>, dim3(4, NE / 128), dim3(256), 0, stream,
                       bufA, ge_w2T, ge_b2, bufB, NE, 512, 512);
    // 11) msg = LN(T5)*g+b; aggr[recv] += msg
    hipLaunchKernelGGL((ln_kernel<1, 512>), dim3(NE / 4), dim3(256), 0, stream,
                       bufB, ge_g, ge_be, (bf16*)nullptr, (float*)nullptr, (const float*)nullptr,
                       recv, aggr, NE);

    // 12) X2 = cat(grid_bf, bf16(aggr)) -> bufA
    hipLaunchKernelGGL(build_x2_kernel, dim3(NG * 128 / 256), dim3(256), 0, stream,
                       grid_bf, aggr, bufA, NG);
    // 13) H3 = relu(X2 @ gn_w1 + b1) -> bufC
    hipLaunchKernelGGL(gemm_bt_kernel<2>, dim3(4, NG / 128), dim3(256), 0, stream,
                       bufA, gn_w1T, gn_b1, bufC, NG, 512, 1024);
    // 14) T8 = H3 @ gn_w2 + b2 -> bufB
    hipLaunchKernelGGL(gemm_bt_kernel<1>, dim3(4, NG / 128), dim3(256), 0, stream,
                       bufC, gn_w2T, gn_b2, bufB, NG, 512, 512);
    // 15) latent = grid + LN(T8)*g+b -> bufA (bf16)
    hipLaunchKernelGGL((ln_kernel<2, 512>), dim3(NG / 4), dim3(256), 0, stream,
                       bufB, gn_g, gn_be, bufA, (float*)nullptr, grid,
                       (const int*)nullptr, (float*)nullptr, NG);

    // 16) H4 = relu(latent @ fin_w1 + b1) -> bufC
    hipLaunchKernelGGL(gemm_bt_kernel<2>, dim3(4, NG / 128), dim3(256), 0, stream,
                       bufA, fin_w1T, fin_b1, bufC, NG, 512, 512);
    // 17) T11 = H4 @ fin_w2 + b2 -> bufB  [N=128]
    hipLaunchKernelGGL(gemm_bt_kernel<1>, dim3(1, NG / 128), dim3(256), 0, stream,
                       bufC, fin_w2T, fin_b2, bufB, NG, 128, 512);
    // 18) out = LN(T11)*g+b -> d_out (f32)
    hipLaunchKernelGGL((ln_kernel<3, 128>), dim3(NG / 4), dim3(256), 0, stream,
                       bufB, fin_g, fin_be, (bf16*)nullptr, (float*)d_out, (const float*)nullptr,
                       (const int*)nullptr, (float*)nullptr, NG);
}

// Round 2
// 460.858 us; speedup vs baseline: 2.7054x; 2.7054x over previous
//
#include <hip/hip_runtime.h>
#include <hip/hip_bf16.h>
#include <stdint.h>

#define LN_EPS 1e-5f

typedef __hip_bfloat16 bf16;
typedef short short8 __attribute__((ext_vector_type(8)));
typedef float f32x4 __attribute__((ext_vector_type(4)));

static __device__ __forceinline__ float bf2f(short s) {
    unsigned int u = ((unsigned int)(unsigned short)s) << 16;
    return __uint_as_float(u);
}
static __device__ __forceinline__ short f2bf(float x) {
    __hip_bfloat16 h = __float2bfloat16(x);
    return *reinterpret_cast<short*>(&h);
}

// async global->LDS, 16B per lane; LDS dest = wave-uniform base + lane*16
static __device__ __forceinline__ void gload16(const void* g, void* l) {
    __builtin_amdgcn_global_load_lds((const __attribute__((address_space(1))) void*)g,
                                     (__attribute__((address_space(3))) void*)l, 16, 0, 0);
}

// ---------------- weight transpose + bf16 convert ----------------
struct TDesc { const float* src; bf16* dst; int K; int N; int kOff; };
struct TDescs { TDesc d[9]; };

__global__ void transpose_all_kernel(TDescs descs) {
    TDesc t = descs.d[blockIdx.z];
    int kb = blockIdx.x * 32, nb = blockIdx.y * 32;
    if (kb >= t.K || nb >= t.N) return;
    __shared__ float tile[32][33];
    int tx = threadIdx.x & 31, ty = threadIdx.x >> 5;
    for (int i = ty; i < 32; i += 8) {
        int k = kb + i, n = nb + tx;
        tile[i][tx] = (k < t.K && n < t.N) ? t.src[(size_t)(t.kOff + k) * t.N + n] : 0.f;
    }
    __syncthreads();
    for (int i = ty; i < 32; i += 8) {
        int n = nb + i, k = kb + tx;
        if (n < t.N && k < t.K)
            t.dst[(size_t)n * t.K + k] = __float2bfloat16(tile[tx][i]);
    }
}

// ---------------- f32 -> bf16 convert ----------------
__global__ void cvt_bf16_kernel(const float* __restrict__ src, bf16* __restrict__ dst, int n) {
    int i = blockIdx.x * 256 + threadIdx.x;
    int idx = i * 4;
    if (idx >= n) return;
    float4 v = *(const float4*)(src + idx);
    dst[idx + 0] = __float2bfloat16(v.x);
    dst[idx + 1] = __float2bfloat16(v.y);
    dst[idx + 2] = __float2bfloat16(v.z);
    dst[idx + 3] = __float2bfloat16(v.w);
}

// ---------------- edge MLP layer 1 (K=4, fp32) ----------------
__global__ void edge_l1_kernel(const float* __restrict__ attr, const float* __restrict__ w1,
                               const float* __restrict__ b1, bf16* __restrict__ h1, int E) {
    int idx = blockIdx.x * 256 + threadIdx.x;
    if (idx >= E * 512) return;
    int e = idx >> 9, d = idx & 511;
    float4 a = *(const float4*)(attr + (size_t)e * 4);
    float s = a.x * w1[d] + a.y * w1[512 + d] + a.z * w1[1024 + d] + a.w * w1[1536 + d] + b1[d];
    h1[idx] = __float2bfloat16(fmaxf(s, 0.f));
}

// ---------------- m97-style bf16 MFMA GEMM: C[M,N] = A[M,K] * BT[N,K]^T ----------------
// linear LDS [128][64], global_load_lds width-16 staging, 2-barrier K-loop.
// EPI: 0 = none, 1 = +bias, 2 = +bias+relu.  Output bf16.
template <int EPI>
__global__ __launch_bounds__(256, 2) void gemm_bt_kernel(
    const bf16* __restrict__ A, const bf16* __restrict__ BT,
    const float* __restrict__ bias, bf16* __restrict__ C, int M, int N, int K) {
    __shared__ short As[128 * 64];
    __shared__ short Bs[128 * 64];
    const int t = threadIdx.x;
    const int lane = t & 63, w = t >> 6;
    const int wm = w >> 1, wn = w & 1;
    const int lr = lane & 15, lh = lane >> 4;
    const int row0 = blockIdx.y * 128;
    const int col0 = blockIdx.x * 128;

    // staging geometry: wave w covers rows [w*32, w*32+32); per instr i: 8 rows
    const int srow = w * 32 + (lane >> 3);
    const int scol = (lane & 7) * 8;
    const bf16* ga = A + (size_t)(row0 + srow) * K + scol;
    const bf16* gb = BT + (size_t)(col0 + srow) * K + scol;
    short* la = As + w * 32 * 64;
    short* lb = Bs + w * 32 * 64;

    f32x4 acc[4][4];
#pragma unroll
    for (int i = 0; i < 4; i++)
#pragma unroll
        for (int j = 0; j < 4; j++) acc[i][j] = {0.f, 0.f, 0.f, 0.f};

    for (int k0 = 0; k0 < K; k0 += 64) {
#pragma unroll
        for (int i = 0; i < 4; i++) {
            gload16(ga + (size_t)i * 8 * K + k0, la + i * 8 * 64);
            gload16(gb + (size_t)i * 8 * K + k0, lb + i * 8 * 64);
        }
        __syncthreads();
#pragma unroll
        for (int kk = 0; kk < 64; kk += 32) {
            short8 af[4], bfv[4];
#pragma unroll
            for (int mf = 0; mf < 4; mf++)
                af[mf] = *(const short8*)&As[(wm * 64 + mf * 16 + lr) * 64 + kk + lh * 8];
#pragma unroll
            for (int nf = 0; nf < 4; nf++)
                bfv[nf] = *(const short8*)&Bs[(wn * 64 + nf * 16 + lr) * 64 + kk + lh * 8];
#pragma unroll
            for (int mf = 0; mf < 4; mf++)
#pragma unroll
                for (int nf = 0; nf < 4; nf++)
                    acc[mf][nf] = __builtin_amdgcn_mfma_f32_16x16x32_bf16(
                        af[mf], bfv[nf], acc[mf][nf], 0, 0, 0);
        }
        __syncthreads();
    }

#pragma unroll
    for (int nf = 0; nf < 4; nf++) {
        int col = col0 + wn * 64 + nf * 16 + lr;
        float bv = (EPI >= 1) ? bias[col] : 0.f;
#pragma unroll
        for (int mf = 0; mf < 4; mf++) {
#pragma unroll
            for (int r = 0; r < 4; r++) {
                int row = row0 + wm * 64 + mf * 16 + lh * 4 + r;
                if (row < M) {
                    float v = acc[mf][nf][r] + bv;
                    if (EPI == 2) v = fmaxf(v, 0.f);
                    C[(size_t)row * N + col] = __float2bfloat16(v);
                }
            }
        }
    }
}

// ---------------- per-edge combine: H2 = relu(T3 + grid_proj[recv] + mesh_proj[send] + b1) ----------------
__global__ void edge_combine_kernel(bf16* __restrict__ T3, const bf16* __restrict__ gridp,
                                    const bf16* __restrict__ meshp, const float* __restrict__ b1,
                                    const int* __restrict__ send, const int* __restrict__ recv, int E) {
    int idx = blockIdx.x * 256 + threadIdx.x;
    if (idx >= E * 64) return;
    int e = idx >> 6;
    int d0 = (idx & 63) * 8;
    int sn = send[e], rn = recv[e];
    short8 tv = *(const short8*)(T3 + (size_t)e * 512 + d0);
    short8 gp = *(const short8*)(gridp + (size_t)rn * 512 + d0);
    short8 mp = *(const short8*)(meshp + (size_t)sn * 512 + d0);
    float4 bA = *(const float4*)(b1 + d0);
    float4 bB = *(const float4*)(b1 + d0 + 4);
    float bb[8] = {bA.x, bA.y, bA.z, bA.w, bB.x, bB.y, bB.z, bB.w};
    short8 o;
#pragma unroll
    for (int j = 0; j < 8; j++)
        o[j] = f2bf(fmaxf(bf2f(tv[j]) + bf2f(gp[j]) + bf2f(mp[j]) + bb[j], 0.f));
    *(short8*)(T3 + (size_t)e * 512 + d0) = o;
}

// ---------------- LayerNorm family: one wave per row ----------------
// MODE 0: out bf16 = LN(x)*g+b           (DN=512)
// MODE 2: out bf16 = resid_f32 + LN(x)*g+b (DN=512)
// MODE 3: out f32 = LN(x)*g+b            (DN=128)
template <int MODE, int DN>
__global__ void ln_kernel(const bf16* __restrict__ X, const float* __restrict__ gw,
                          const float* __restrict__ bw, bf16* __restrict__ outb,
                          float* __restrict__ outf, const float* __restrict__ resid, int R) {
    constexpr int EPL = DN / 64;
    int row = blockIdx.x * 4 + (threadIdx.x >> 6);
    if (row >= R) return;
    int lane = threadIdx.x & 63;
    const bf16* xr = X + (size_t)row * DN + lane * EPL;
    float v[EPL];
    if constexpr (EPL == 8) {
        short8 t8 = *(const short8*)xr;
#pragma unroll
        for (int j = 0; j < 8; j++) v[j] = bf2f(t8[j]);
    } else {
#pragma unroll
        for (int j = 0; j < EPL; j++) v[j] = __bfloat162float(xr[j]);
    }
    float s = 0.f, s2 = 0.f;
#pragma unroll
    for (int j = 0; j < EPL; j++) { s += v[j]; s2 += v[j] * v[j]; }
#pragma unroll
    for (int o = 32; o > 0; o >>= 1) {
        s += __shfl_xor(s, o, 64);
        s2 += __shfl_xor(s2, o, 64);
    }
    float mu = s * (1.f / DN);
    float var = s2 * (1.f / DN) - mu * mu;
    float rs = rsqrtf(var + LN_EPS);
    int d0 = lane * EPL;

    if constexpr (MODE == 0) {
        short8 o;
#pragma unroll
        for (int j = 0; j < EPL; j++)
            o[j] = f2bf((v[j] - mu) * rs * gw[d0 + j] + bw[d0 + j]);
        *(short8*)(outb + (size_t)row * DN + d0) = o;
    } else if constexpr (MODE == 2) {
        short8 o;
#pragma unroll
        for (int j = 0; j < EPL; j++) {
            float y = (v[j] - mu) * rs * gw[d0 + j] + bw[d0 + j];
            o[j] = f2bf(resid[(size_t)row * DN + d0 + j] + y);
        }
        *(short8*)(outb + (size_t)row * DN + d0) = o;
    } else {
#pragma unroll
        for (int j = 0; j < EPL; j++)
            outf[(size_t)row * DN + d0 + j] = (v[j] - mu) * rs * gw[d0 + j] + bw[d0 + j];
    }
}

// ---------------- CSR build ----------------
__global__ void degree_kernel(const int* __restrict__ recv, int* __restrict__ deg, int E) {
    int e = blockIdx.x * 256 + threadIdx.x;
    if (e < E) atomicAdd(&deg[recv[e]], 1);
}

// single block, 1024 threads x 16 elems = 16384; exclusive scan -> off[0..16384]
__global__ void scan_kernel(const int* __restrict__ deg, int* __restrict__ off) {
    __shared__ int partial[1024];
    int t = threadIdx.x;
    int base = t * 16;
    int v[16];
    int s = 0;
#pragma unroll
    for (int i = 0; i < 16; i++) { v[i] = deg[base + i]; s += v[i]; }
    partial[t] = s;
    __syncthreads();
    for (int o = 1; o < 1024; o <<= 1) {
        int x = (t >= o) ? partial[t - o] : 0;
        __syncthreads();
        partial[t] += x;
        __syncthreads();
    }
    int run = (t == 0) ? 0 : partial[t - 1];
#pragma unroll
    for (int i = 0; i < 16; i++) { off[base + i] = run; run += v[i]; }
    if (t == 1023) off[16384] = run;
}

__global__ void scatter_kernel(const int* __restrict__ recv, const int* __restrict__ off,
                               int* __restrict__ cnt, int* __restrict__ edges, int E) {
    int e = blockIdx.x * 256 + threadIdx.x;
    if (e < E) {
        int r = recv[e];
        int p = atomicAdd(&cnt[r], 1);
        edges[off[r] + p] = e;
    }
}

// ---------------- aggregate msg by receiver + build X2 = cat(grid_bf, aggr) ----------------
__global__ void aggregate_kernel(const bf16* __restrict__ msg, const bf16* __restrict__ gridb,
                                 const int* __restrict__ off, const int* __restrict__ edges,
                                 bf16* __restrict__ X2, int G) {
    int g = blockIdx.x * 4 + (threadIdx.x >> 6);
    if (g >= G) return;
    int lane = threadIdx.x & 63;
    int d0 = lane * 8;
    float s[8] = {0.f, 0.f, 0.f, 0.f, 0.f, 0.f, 0.f, 0.f};
    int a = off[g], b = off[g + 1];
    for (int i = a; i < b; i++) {
        int e = edges[i];
        short8 m = *(const short8*)(msg + (size_t)e * 512 + d0);
#pragma unroll
        for (int j = 0; j < 8; j++) s[j] += bf2f(m[j]);
    }
    *(short8*)(X2 + (size_t)g * 1024 + d0) = *(const short8*)(gridb + (size_t)g * 512 + d0);
    short8 o;
#pragma unroll
    for (int j = 0; j < 8; j++) o[j] = f2bf(s[j]);
    *(short8*)(X2 + (size_t)g * 1024 + 512 + d0) = o;
}

extern "C" void kernel_launch(void* const* d_in, const int* in_sizes, int n_in,
                              void* d_out, int out_size, void* d_ws, size_t ws_size,
                              hipStream_t stream) {
    const int NM = 2562, NG = 16384, NE = 49152;
    const float* mesh   = (const float*)d_in[0];
    const float* grid   = (const float*)d_in[1];
    const float* attr   = (const float*)d_in[2];
    const int*   eidx   = (const int*)d_in[3];
    const int*   send   = eidx;
    const int*   recv   = eidx + NE;
    const float* emlp_w1 = (const float*)d_in[4];
    const float* emlp_b1 = (const float*)d_in[5];
    const float* emlp_w2 = (const float*)d_in[6];
    const float* emlp_b2 = (const float*)d_in[7];
    const float* emlp_g  = (const float*)d_in[8];
    const float* emlp_be = (const float*)d_in[9];
    const float* ge_w1 = (const float*)d_in[10];
    const float* ge_b1 = (const float*)d_in[11];
    const float* ge_w2 = (const float*)d_in[12];
    const float* ge_b2 = (const float*)d_in[13];
    const float* ge_g  = (const float*)d_in[14];
    const float* ge_be = (const float*)d_in[15];
    const float* gn_w1 = (const float*)d_in[16];
    const float* gn_b1 = (const float*)d_in[17];
    const float* gn_w2 = (const float*)d_in[18];
    const float* gn_b2 = (const float*)d_in[19];
    const float* gn_g  = (const float*)d_in[20];
    const float* gn_be = (const float*)d_in[21];
    const float* fin_w1 = (const float*)d_in[22];
    const float* fin_b1 = (const float*)d_in[23];
    const float* fin_w2 = (const float*)d_in[24];
    const float* fin_b2 = (const float*)d_in[25];
    const float* fin_g  = (const float*)d_in[26];
    const float* fin_be = (const float*)d_in[27];

    char* p = (char*)d_ws;
    auto take = [&](size_t bytes) -> char* {
        char* r = p;
        p += (bytes + 255) & ~(size_t)255;
        return r;
    };
    bf16* emlp_w2T = (bf16*)take((size_t)512 * 512 * 2);
    bf16* geA_T    = (bf16*)take((size_t)512 * 512 * 2);
    bf16* geB_T    = (bf16*)take((size_t)512 * 512 * 2);
    bf16* geC_T    = (bf16*)take((size_t)512 * 512 * 2);
    bf16* ge_w2T   = (bf16*)take((size_t)512 * 512 * 2);
    bf16* gn_w1T   = (bf16*)take((size_t)512 * 1024 * 2);
    bf16* gn_w2T   = (bf16*)take((size_t)512 * 512 * 2);
    bf16* fin_w1T  = (bf16*)take((size_t)512 * 512 * 2);
    bf16* fin_w2T  = (bf16*)take((size_t)128 * 512 * 2);
    bf16* grid_bf  = (bf16*)take((size_t)NG * 512 * 2);
    bf16* mesh_bf  = (bf16*)take((size_t)NM * 512 * 2);
    bf16* bufA     = (bf16*)take((size_t)NE * 512 * 2);  // H1 -> T3/H2 -> X2 -> latent
    bf16* bufB     = (bf16*)take((size_t)NE * 512 * 2);  // T2/edges_emb -> T5/msg -> T8 -> T11
    bf16* bufC     = (bf16*)take((size_t)NG * 512 * 2);  // grid_proj -> H3 -> H4
    bf16* bufD     = (bf16*)take((size_t)NM * 512 * 2);  // mesh_proj
    int*  deg      = (int*)take((size_t)NG * 4);
    int*  cnt      = (int*)take((size_t)NG * 4);
    int*  csr_off  = (int*)take((size_t)(NG + 1) * 4);
    int*  csr_edge = (int*)take((size_t)NE * 4);

    // 1) transpose + bf16-convert all GEMM weights
    TDescs td;
    td.d[0] = {emlp_w2, emlp_w2T, 512, 512, 0};
    td.d[1] = {ge_w1,   geA_T,    512, 512, 0};
    td.d[2] = {ge_w1,   geB_T,    512, 512, 512};
    td.d[3] = {ge_w1,   geC_T,    512, 512, 1024};
    td.d[4] = {ge_w2,   ge_w2T,   512, 512, 0};
    td.d[5] = {gn_w1,   gn_w1T,  1024, 512, 0};
    td.d[6] = {gn_w2,   gn_w2T,   512, 512, 0};
    td.d[7] = {fin_w1,  fin_w1T,  512, 512, 0};
    td.d[8] = {fin_w2,  fin_w2T,  512, 128, 0};
    hipLaunchKernelGGL(transpose_all_kernel, dim3(32, 16, 9), dim3(256), 0, stream, td);

    // 2) bf16 inputs + CSR build (independent of MLP pipeline)
    hipLaunchKernelGGL(cvt_bf16_kernel, dim3((NG * 512 / 4 + 255) / 256), dim3(256), 0, stream,
                       grid, grid_bf, NG * 512);
    hipLaunchKernelGGL(cvt_bf16_kernel, dim3((NM * 512 / 4 + 255) / 256), dim3(256), 0, stream,
                       mesh, mesh_bf, NM * 512);
    hipMemsetAsync(deg, 0, (size_t)NG * 4, stream);
    hipMemsetAsync(cnt, 0, (size_t)NG * 4, stream);
    hipLaunchKernelGGL(degree_kernel, dim3((NE + 255) / 256), dim3(256), 0, stream, recv, deg, NE);
    hipLaunchKernelGGL(scan_kernel, dim3(1), dim3(1024), 0, stream, deg, csr_off);
    hipLaunchKernelGGL(scatter_kernel, dim3((NE + 255) / 256), dim3(256), 0, stream,
                       recv, csr_off, cnt, csr_edge, NE);

    // 3) edge MLP layer1: H1 = relu(attr @ emlp_w1 + b1) -> bufA
    hipLaunchKernelGGL(edge_l1_kernel, dim3(NE * 512 / 256), dim3(256), 0, stream,
                       attr, emlp_w1, emlp_b1, bufA, NE);
    // 4) T2 = H1 @ emlp_w2 + b2 -> bufB
    hipLaunchKernelGGL(gemm_bt_kernel<1>, dim3(4, NE / 128), dim3(256), 0, stream,
                       bufA, emlp_w2T, emlp_b2, bufB, NE, 512, 512);
    // 5) edges_emb = LN(T2)*g+b (in place, bufB)
    hipLaunchKernelGGL((ln_kernel<0, 512>), dim3(NE / 4), dim3(256), 0, stream,
                       bufB, emlp_g, emlp_be, bufB, (float*)nullptr, (const float*)nullptr, NE);

    // 6) grid_proj = grid_bf @ ge_w1[0:512] -> bufC
    hipLaunchKernelGGL(gemm_bt_kernel<0>, dim3(4, NG / 128), dim3(256), 0, stream,
                       grid_bf, geA_T, (const float*)nullptr, bufC, NG, 512, 512);
    // 7) mesh_proj = mesh_bf @ ge_w1[512:1024] -> bufD
    hipLaunchKernelGGL(gemm_bt_kernel<0>, dim3(4, (NM + 127) / 128), dim3(256), 0, stream,
                       mesh_bf, geB_T, (const float*)nullptr, bufD, NM, 512, 512);
    // 8) T3 = edges_emb @ ge_w1[1024:1536] -> bufA
    hipLaunchKernelGGL(gemm_bt_kernel<0>, dim3(4, NE / 128), dim3(256), 0, stream,
                       bufB, geC_T, (const float*)nullptr, bufA, NE, 512, 512);
    // 9) H2 = relu(T3 + grid_proj[recv] + mesh_proj[send] + ge_b1) (in place, bufA)
    hipLaunchKernelGGL(edge_combine_kernel, dim3(NE * 64 / 256), dim3(256), 0, stream,
                       bufA, bufC, bufD, ge_b1, send, recv, NE);
    // 10) T5 = H2 @ ge_w2 + b2 -> bufB
    hipLaunchKernelGGL(gemm_bt_kernel<1>, dim3(4, NE / 128), dim3(256), 0, stream,
                       bufA, ge_w2T, ge_b2, bufB, NE, 512, 512);
    // 11) msg = LN(T5)*g+b (in place, bufB)
    hipLaunchKernelGGL((ln_kernel<0, 512>), dim3(NE / 4), dim3(256), 0, stream,
                       bufB, ge_g, ge_be, bufB, (float*)nullptr, (const float*)nullptr, NE);
    // 12) X2 = cat(grid_bf, segment_sum(msg)) -> bufA (CSR gather-reduce, no atomics)
    hipLaunchKernelGGL(aggregate_kernel, dim3(NG / 4), dim3(256), 0, stream,
                       bufB, grid_bf, csr_off, csr_edge, bufA, NG);

    // 13) H3 = relu(X2 @ gn_w1 + b1) -> bufC
    hipLaunchKernelGGL(gemm_bt_kernel<2>, dim3(4, NG / 128), dim3(256), 0, stream,
                       bufA, gn_w1T, gn_b1, bufC, NG, 512, 1024);
    // 14) T8 = H3 @ gn_w2 + b2 -> bufB
    hipLaunchKernelGGL(gemm_bt_kernel<1>, dim3(4, NG / 128), dim3(256), 0, stream,
                       bufC, gn_w2T, gn_b2, bufB, NG, 512, 512);
    // 15) latent = grid + LN(T8)*g+b -> bufA (bf16)
    hipLaunchKernelGGL((ln_kernel<2, 512>), dim3(NG / 4), dim3(256), 0, stream,
                       bufB, gn_g, gn_be, bufA, (float*)nullptr, grid, NG);

    // 16) H4 = relu(latent @ fin_w1 + b1) -> bufC
    hipLaunchKernelGGL(gemm_bt_kernel<2>, dim3(4, NG / 128), dim3(256), 0, stream,
                       bufA, fin_w1T, fin_b1, bufC, NG, 512, 512);
    // 17) T11 = H4 @ fin_w2 + b2 -> bufB  [N=128]
    hipLaunchKernelGGL(gemm_bt_kernel<1>, dim3(1, NG / 128), dim3(256), 0, stream,
                       bufC, fin_w2T, fin_b2, bufB, NG, 128, 512);
    // 18) out = LN(T11)*g+b -> d_out (f32)
    hipLaunchKernelGGL((ln_kernel<3, 128>), dim3(NG / 4), dim3(256), 0, stream,
                       bufB, fin_g, fin_be, (bf16*)nullptr, (float*)d_out, (const float*)nullptr, NG);
}

// Round 3
// 449.972 us; speedup vs baseline: 2.7708x; 1.0242x over previous
//
#include <hip/hip_runtime.h>
#include <hip/hip_bf16.h>
#include <stdint.h>

#define LN_EPS 1e-5f

typedef __hip_bfloat16 bf16;
typedef short short8 __attribute__((ext_vector_type(8)));
typedef float f32x4 __attribute__((ext_vector_type(4)));

static __device__ __forceinline__ float bf2f(short s) {
    unsigned int u = ((unsigned int)(unsigned short)s) << 16;
    return __uint_as_float(u);
}
static __device__ __forceinline__ short f2bf(float x) {
    __hip_bfloat16 h = __float2bfloat16(x);
    return *reinterpret_cast<short*>(&h);
}

// async global->LDS, 16B per lane; LDS dest = wave-uniform base + lane*16
static __device__ __forceinline__ void gload16(const void* g, void* l) {
    __builtin_amdgcn_global_load_lds((const __attribute__((address_space(1))) void*)g,
                                     (__attribute__((address_space(3))) void*)l, 16, 0, 0);
}

// ---------------- weight transpose + bf16 convert ----------------
struct TDesc { const float* src; bf16* dst; int K; int N; int kOff; };
struct TDescs { TDesc d[9]; };

__global__ void transpose_all_kernel(TDescs descs) {
    TDesc t = descs.d[blockIdx.z];
    int kb = blockIdx.x * 32, nb = blockIdx.y * 32;
    if (kb >= t.K || nb >= t.N) return;
    __shared__ float tile[32][33];
    int tx = threadIdx.x & 31, ty = threadIdx.x >> 5;
    for (int i = ty; i < 32; i += 8) {
        int k = kb + i, n = nb + tx;
        tile[i][tx] = (k < t.K && n < t.N) ? t.src[(size_t)(t.kOff + k) * t.N + n] : 0.f;
    }
    __syncthreads();
    for (int i = ty; i < 32; i += 8) {
        int n = nb + i, k = kb + tx;
        if (n < t.N && k < t.K)
            t.dst[(size_t)n * t.K + k] = __float2bfloat16(tile[tx][i]);
    }
}

// ---------------- f32 -> bf16 convert ----------------
__global__ void cvt_bf16_kernel(const float* __restrict__ src, bf16* __restrict__ dst, int n) {
    int i = blockIdx.x * 256 + threadIdx.x;
    int idx = i * 4;
    if (idx >= n) return;
    float4 v = *(const float4*)(src + idx);
    dst[idx + 0] = __float2bfloat16(v.x);
    dst[idx + 1] = __float2bfloat16(v.y);
    dst[idx + 2] = __float2bfloat16(v.z);
    dst[idx + 3] = __float2bfloat16(v.w);
}

// ---------------- edge MLP layer 1 (K=4, fp32) ----------------
__global__ void edge_l1_kernel(const float* __restrict__ attr, const float* __restrict__ w1,
                               const float* __restrict__ b1, bf16* __restrict__ h1, int E) {
    int idx = blockIdx.x * 256 + threadIdx.x;
    if (idx >= E * 512) return;
    int e = idx >> 9, d = idx & 511;
    float4 a = *(const float4*)(attr + (size_t)e * 4);
    float s = a.x * w1[d] + a.y * w1[512 + d] + a.z * w1[1024 + d] + a.w * w1[1536 + d] + b1[d];
    h1[idx] = __float2bfloat16(fmaxf(s, 0.f));
}

// ---------------- bf16 MFMA GEMM: C[M,N] = A[M,K] * BT[N,K]^T ----------------
// 2-phase prefetch: double-buffered LDS, counted vmcnt (never 0 mid-loop),
// raw s_barrier (no compiler vmcnt drain), XCD-bijective block swizzle.
// EPI: 0 = none, 1 = +bias, 2 = +bias+relu.  Output bf16.
template <int EPI>
__global__ __launch_bounds__(256, 2) void gemm_bt_kernel(
    const bf16* __restrict__ A, const bf16* __restrict__ BT,
    const float* __restrict__ bias, bf16* __restrict__ C, int M, int N, int K) {
    __shared__ short As[2][128 * 64];
    __shared__ short Bs[2][128 * 64];
    const int t = threadIdx.x;
    const int lane = t & 63, w = t >> 6;
    const int wm = w >> 1, wn = w & 1;
    const int lr = lane & 15, lh = lane >> 4;

    // bijective XCD swizzle (m204): XCD k = orig%8 gets a contiguous tile range
    int nwg = gridDim.x * gridDim.y;
    int orig = blockIdx.y * gridDim.x + blockIdx.x;
    int q = nwg >> 3, r = nwg & 7;
    int xcd = orig & 7, loc = orig >> 3;
    int wg = (xcd < r ? xcd * (q + 1) : r * (q + 1) + (xcd - r) * q) + loc;
    int bx = wg % gridDim.x, by = wg / gridDim.x;
    const int row0 = by * 128;
    const int col0 = bx * 128;

    // staging geometry: wave w covers rows [w*32, w*32+32); instr i: rows +i*8
    const int srow = w * 32 + (lane >> 3);
    const int scol = (lane & 7) * 8;
    // clamp OOB rows to keep exactly 8 loads/wave in flight (vmcnt accounting)
    const bf16* gaP[4];
    const bf16* gbP[4];
#pragma unroll
    for (int i = 0; i < 4; i++) {
        int ra = row0 + srow + i * 8; if (ra >= M) ra = M - 1;
        int rb = col0 + srow + i * 8; if (rb >= N) rb = N - 1;
        gaP[i] = A + (size_t)ra * K + scol;
        gbP[i] = BT + (size_t)rb * K + scol;
    }
    short* laBase0 = &As[0][w * 32 * 64];
    short* lbBase0 = &Bs[0][w * 32 * 64];
    short* laBase1 = &As[1][w * 32 * 64];
    short* lbBase1 = &Bs[1][w * 32 * 64];

    f32x4 acc[4][4];
#pragma unroll
    for (int i = 0; i < 4; i++)
#pragma unroll
        for (int j = 0; j < 4; j++) acc[i][j] = {0.f, 0.f, 0.f, 0.f};

    const int T = K >> 6;
    // prologue: stage tile 0 into buf 0
#pragma unroll
    for (int i = 0; i < 4; i++) {
        gload16(gaP[i], laBase0 + i * 8 * 64);
        gload16(gbP[i], lbBase0 + i * 8 * 64);
    }

    int cur = 0;
    for (int tt = 0; tt < T; ++tt) {
        if (tt + 1 < T) {
            int k0 = (tt + 1) << 6;
            short* la = cur ? laBase0 : laBase1;
            short* lb = cur ? lbBase0 : lbBase1;
#pragma unroll
            for (int i = 0; i < 4; i++) {
                gload16(gaP[i] + k0, la + i * 8 * 64);
                gload16(gbP[i] + k0, lb + i * 8 * 64);
            }
            asm volatile("s_waitcnt vmcnt(8)" ::: "memory");
        } else {
            asm volatile("s_waitcnt vmcnt(0)" ::: "memory");
        }
        __builtin_amdgcn_s_barrier();
        asm volatile("" ::: "memory");

        const short* Ac = As[cur];
        const short* Bc = Bs[cur];
#pragma unroll
        for (int kk = 0; kk < 64; kk += 32) {
            short8 af[4], bfv[4];
#pragma unroll
            for (int mf = 0; mf < 4; mf++)
                af[mf] = *(const short8*)&Ac[(wm * 64 + mf * 16 + lr) * 64 + kk + lh * 8];
#pragma unroll
            for (int nf = 0; nf < 4; nf++)
                bfv[nf] = *(const short8*)&Bc[(wn * 64 + nf * 16 + lr) * 64 + kk + lh * 8];
#pragma unroll
            for (int mf = 0; mf < 4; mf++)
#pragma unroll
                for (int nf = 0; nf < 4; nf++)
                    acc[mf][nf] = __builtin_amdgcn_mfma_f32_16x16x32_bf16(
                        af[mf], bfv[nf], acc[mf][nf], 0, 0, 0);
        }
        asm volatile("" ::: "memory");
        __builtin_amdgcn_s_barrier();
        cur ^= 1;
    }

#pragma unroll
    for (int nf = 0; nf < 4; nf++) {
        int col = col0 + wn * 64 + nf * 16 + lr;
        float bv = (EPI >= 1) ? bias[col] : 0.f;
#pragma unroll
        for (int mf = 0; mf < 4; mf++) {
#pragma unroll
            for (int r2 = 0; r2 < 4; r2++) {
                int row = row0 + wm * 64 + mf * 16 + lh * 4 + r2;
                if (row < M && col < N) {
                    float v = acc[mf][nf][r2] + bv;
                    if (EPI == 2) v = fmaxf(v, 0.f);
                    C[(size_t)row * N + col] = __float2bfloat16(v);
                }
            }
        }
    }
}

// ---------------- per-edge combine: H2 = relu(T3 + grid_proj[recv] + mesh_proj[send] + b1) ----------------
__global__ void edge_combine_kernel(bf16* __restrict__ T3, const bf16* __restrict__ gridp,
                                    const bf16* __restrict__ meshp, const float* __restrict__ b1,
                                    const int* __restrict__ send, const int* __restrict__ recv, int E) {
    int idx = blockIdx.x * 256 + threadIdx.x;
    if (idx >= E * 64) return;
    int e = idx >> 6;
    int d0 = (idx & 63) * 8;
    int sn = send[e], rn = recv[e];
    short8 tv = *(const short8*)(T3 + (size_t)e * 512 + d0);
    short8 gp = *(const short8*)(gridp + (size_t)rn * 512 + d0);
    short8 mp = *(const short8*)(meshp + (size_t)sn * 512 + d0);
    float4 bA = *(const float4*)(b1 + d0);
    float4 bB = *(const float4*)(b1 + d0 + 4);
    float bb[8] = {bA.x, bA.y, bA.z, bA.w, bB.x, bB.y, bB.z, bB.w};
    short8 o;
#pragma unroll
    for (int j = 0; j < 8; j++)
        o[j] = f2bf(fmaxf(bf2f(tv[j]) + bf2f(gp[j]) + bf2f(mp[j]) + bb[j], 0.f));
    *(short8*)(T3 + (size_t)e * 512 + d0) = o;
}

// ---------------- LayerNorm family: one wave per row ----------------
// MODE 0: out bf16 = LN(x)*g+b           (DN=512)
// MODE 2: out bf16 = resid_f32 + LN(x)*g+b (DN=512)
// MODE 3: out f32 = LN(x)*g+b            (DN=128)
template <int MODE, int DN>
__global__ void ln_kernel(const bf16* __restrict__ X, const float* __restrict__ gw,
                          const float* __restrict__ bw, bf16* __restrict__ outb,
                          float* __restrict__ outf, const float* __restrict__ resid, int R) {
    constexpr int EPL = DN / 64;
    int row = blockIdx.x * 4 + (threadIdx.x >> 6);
    if (row >= R) return;
    int lane = threadIdx.x & 63;
    const bf16* xr = X + (size_t)row * DN + lane * EPL;
    float v[EPL];
    if constexpr (EPL == 8) {
        short8 t8 = *(const short8*)xr;
#pragma unroll
        for (int j = 0; j < 8; j++) v[j] = bf2f(t8[j]);
    } else {
#pragma unroll
        for (int j = 0; j < EPL; j++) v[j] = __bfloat162float(xr[j]);
    }
    float s = 0.f, s2 = 0.f;
#pragma unroll
    for (int j = 0; j < EPL; j++) { s += v[j]; s2 += v[j] * v[j]; }
#pragma unroll
    for (int o = 32; o > 0; o >>= 1) {
        s += __shfl_xor(s, o, 64);
        s2 += __shfl_xor(s2, o, 64);
    }
    float mu = s * (1.f / DN);
    float var = s2 * (1.f / DN) - mu * mu;
    float rs = rsqrtf(var + LN_EPS);
    int d0 = lane * EPL;

    if constexpr (MODE == 0) {
        short8 o;
#pragma unroll
        for (int j = 0; j < EPL; j++)
            o[j] = f2bf((v[j] - mu) * rs * gw[d0 + j] + bw[d0 + j]);
        *(short8*)(outb + (size_t)row * DN + d0) = o;
    } else if constexpr (MODE == 2) {
        short8 o;
#pragma unroll
        for (int j = 0; j < EPL; j++) {
            float y = (v[j] - mu) * rs * gw[d0 + j] + bw[d0 + j];
            o[j] = f2bf(resid[(size_t)row * DN + d0 + j] + y);
        }
        *(short8*)(outb + (size_t)row * DN + d0) = o;
    } else {
#pragma unroll
        for (int j = 0; j < EPL; j++)
            outf[(size_t)row * DN + d0 + j] = (v[j] - mu) * rs * gw[d0 + j] + bw[d0 + j];
    }
}

// ---------------- LN stats only: stats[row] = {mu, rsqrt(var+eps)} (DN=512) ----------------
__global__ void ln_stats_kernel(const bf16* __restrict__ X, float2* __restrict__ stats, int R) {
    int row = blockIdx.x * 4 + (threadIdx.x >> 6);
    if (row >= R) return;
    int lane = threadIdx.x & 63;
    short8 t8 = *(const short8*)(X + (size_t)row * 512 + lane * 8);
    float s = 0.f, s2 = 0.f;
#pragma unroll
    for (int j = 0; j < 8; j++) {
        float x = bf2f(t8[j]);
        s += x; s2 += x * x;
    }
#pragma unroll
    for (int o = 32; o > 0; o >>= 1) {
        s += __shfl_xor(s, o, 64);
        s2 += __shfl_xor(s2, o, 64);
    }
    float mu = s * (1.f / 512.f);
    float var = s2 * (1.f / 512.f) - mu * mu;
    if (lane == 0) stats[row] = make_float2(mu, rsqrtf(var + LN_EPS));
}

// ---------------- CSR build ----------------
__global__ void degree_kernel(const int* __restrict__ recv, int* __restrict__ deg, int E) {
    int e = blockIdx.x * 256 + threadIdx.x;
    if (e < E) atomicAdd(&deg[recv[e]], 1);
}

__global__ void scan_kernel(const int* __restrict__ deg, int* __restrict__ off) {
    __shared__ int partial[1024];
    int t = threadIdx.x;
    int base = t * 16;
    int v[16];
    int s = 0;
#pragma unroll
    for (int i = 0; i < 16; i++) { v[i] = deg[base + i]; s += v[i]; }
    partial[t] = s;
    __syncthreads();
    for (int o = 1; o < 1024; o <<= 1) {
        int x = (t >= o) ? partial[t - o] : 0;
        __syncthreads();
        partial[t] += x;
        __syncthreads();
    }
    int run = (t == 0) ? 0 : partial[t - 1];
#pragma unroll
    for (int i = 0; i < 16; i++) { off[base + i] = run; run += v[i]; }
    if (t == 1023) off[16384] = run;
}

__global__ void scatter_kernel(const int* __restrict__ recv, const int* __restrict__ off,
                               int* __restrict__ cnt, int* __restrict__ edges, int E) {
    int e = blockIdx.x * 256 + threadIdx.x;
    if (e < E) {
        int r = recv[e];
        int p = atomicAdd(&cnt[r], 1);
        edges[off[r] + p] = e;
    }
}

// ---------------- aggregate LN(msg) by receiver + build X2 = cat(grid_bf, aggr) ----------------
// msg LN applied on the fly from per-row stats: y = (x-mu)*rs*g+b
__global__ void aggregate_kernel(const bf16* __restrict__ T5, const float2* __restrict__ stats,
                                 const float* __restrict__ gw, const float* __restrict__ bw,
                                 const bf16* __restrict__ gridb,
                                 const int* __restrict__ off, const int* __restrict__ edges,
                                 bf16* __restrict__ X2, int G) {
    int g = blockIdx.x * 4 + (threadIdx.x >> 6);
    if (g >= G) return;
    int lane = threadIdx.x & 63;
    int d0 = lane * 8;
    float gg[8], bb[8];
    {
        float4 a = *(const float4*)(gw + d0), b = *(const float4*)(gw + d0 + 4);
        gg[0]=a.x; gg[1]=a.y; gg[2]=a.z; gg[3]=a.w; gg[4]=b.x; gg[5]=b.y; gg[6]=b.z; gg[7]=b.w;
        float4 c = *(const float4*)(bw + d0), d = *(const float4*)(bw + d0 + 4);
        bb[0]=c.x; bb[1]=c.y; bb[2]=c.z; bb[3]=c.w; bb[4]=d.x; bb[5]=d.y; bb[6]=d.z; bb[7]=d.w;
    }
    float s[8] = {0.f, 0.f, 0.f, 0.f, 0.f, 0.f, 0.f, 0.f};
    int a = off[g], b = off[g + 1];
    for (int i = a; i < b; i++) {
        int e = edges[i];
        float2 st = stats[e];
        short8 m = *(const short8*)(T5 + (size_t)e * 512 + d0);
#pragma unroll
        for (int j = 0; j < 8; j++)
            s[j] += (bf2f(m[j]) - st.x) * st.y * gg[j] + bb[j];
    }
    *(short8*)(X2 + (size_t)g * 1024 + d0) = *(const short8*)(gridb + (size_t)g * 512 + d0);
    short8 o;
#pragma unroll
    for (int j = 0; j < 8; j++) o[j] = f2bf(s[j]);
    *(short8*)(X2 + (size_t)g * 1024 + 512 + d0) = o;
}

extern "C" void kernel_launch(void* const* d_in, const int* in_sizes, int n_in,
                              void* d_out, int out_size, void* d_ws, size_t ws_size,
                              hipStream_t stream) {
    const int NM = 2562, NG = 16384, NE = 49152;
    const float* mesh   = (const float*)d_in[0];
    const float* grid   = (const float*)d_in[1];
    const float* attr   = (const float*)d_in[2];
    const int*   eidx   = (const int*)d_in[3];
    const int*   send   = eidx;
    const int*   recv   = eidx + NE;
    const float* emlp_w1 = (const float*)d_in[4];
    const float* emlp_b1 = (const float*)d_in[5];
    const float* emlp_w2 = (const float*)d_in[6];
    const float* emlp_b2 = (const float*)d_in[7];
    const float* emlp_g  = (const float*)d_in[8];
    const float* emlp_be = (const float*)d_in[9];
    const float* ge_w1 = (const float*)d_in[10];
    const float* ge_b1 = (const float*)d_in[11];
    const float* ge_w2 = (const float*)d_in[12];
    const float* ge_b2 = (const float*)d_in[13];
    const float* ge_g  = (const float*)d_in[14];
    const float* ge_be = (const float*)d_in[15];
    const float* gn_w1 = (const float*)d_in[16];
    const float* gn_b1 = (const float*)d_in[17];
    const float* gn_w2 = (const float*)d_in[18];
    const float* gn_b2 = (const float*)d_in[19];
    const float* gn_g  = (const float*)d_in[20];
    const float* gn_be = (const float*)d_in[21];
    const float* fin_w1 = (const float*)d_in[22];
    const float* fin_b1 = (const float*)d_in[23];
    const float* fin_w2 = (const float*)d_in[24];
    const float* fin_b2 = (const float*)d_in[25];
    const float* fin_g  = (const float*)d_in[26];
    const float* fin_be = (const float*)d_in[27];

    char* p = (char*)d_ws;
    auto take = [&](size_t bytes) -> char* {
        char* r = p;
        p += (bytes + 255) & ~(size_t)255;
        return r;
    };
    bf16* emlp_w2T = (bf16*)take((size_t)512 * 512 * 2);
    bf16* geA_T    = (bf16*)take((size_t)512 * 512 * 2);
    bf16* geB_T    = (bf16*)take((size_t)512 * 512 * 2);
    bf16* geC_T    = (bf16*)take((size_t)512 * 512 * 2);
    bf16* ge_w2T   = (bf16*)take((size_t)512 * 512 * 2);
    bf16* gn_w1T   = (bf16*)take((size_t)512 * 1024 * 2);
    bf16* gn_w2T   = (bf16*)take((size_t)512 * 512 * 2);
    bf16* fin_w1T  = (bf16*)take((size_t)512 * 512 * 2);
    bf16* fin_w2T  = (bf16*)take((size_t)128 * 512 * 2);
    bf16* grid_bf  = (bf16*)take((size_t)NG * 512 * 2);
    bf16* mesh_bf  = (bf16*)take((size_t)NM * 512 * 2);
    bf16* bufA     = (bf16*)take((size_t)NE * 512 * 2);  // H1 -> T3/H2 -> X2 -> latent
    bf16* bufB     = (bf16*)take((size_t)NE * 512 * 2);  // T2/edges_emb -> T5 -> T8 -> T11
    bf16* bufC     = (bf16*)take((size_t)NG * 512 * 2);  // grid_proj -> H3 -> H4
    bf16* bufD     = (bf16*)take((size_t)NM * 512 * 2);  // mesh_proj
    float2* stats  = (float2*)take((size_t)NE * 8);
    int*  deg      = (int*)take((size_t)NG * 4);
    int*  cnt      = (int*)take((size_t)NG * 4);
    int*  csr_off  = (int*)take((size_t)(NG + 1) * 4);
    int*  csr_edge = (int*)take((size_t)NE * 4);

    // 1) transpose + bf16-convert all GEMM weights
    TDescs td;
    td.d[0] = {emlp_w2, emlp_w2T, 512, 512, 0};
    td.d[1] = {ge_w1,   geA_T,    512, 512, 0};
    td.d[2] = {ge_w1,   geB_T,    512, 512, 512};
    td.d[3] = {ge_w1,   geC_T,    512, 512, 1024};
    td.d[4] = {ge_w2,   ge_w2T,   512, 512, 0};
    td.d[5] = {gn_w1,   gn_w1T,  1024, 512, 0};
    td.d[6] = {gn_w2,   gn_w2T,   512, 512, 0};
    td.d[7] = {fin_w1,  fin_w1T,  512, 512, 0};
    td.d[8] = {fin_w2,  fin_w2T,  512, 128, 0};
    hipLaunchKernelGGL(transpose_all_kernel, dim3(32, 16, 9), dim3(256), 0, stream, td);

    // 2) bf16 inputs + CSR build (independent of MLP pipeline)
    hipLaunchKernelGGL(cvt_bf16_kernel, dim3((NG * 512 / 4 + 255) / 256), dim3(256), 0, stream,
                       grid, grid_bf, NG * 512);
    hipLaunchKernelGGL(cvt_bf16_kernel, dim3((NM * 512 / 4 + 255) / 256), dim3(256), 0, stream,
                       mesh, mesh_bf, NM * 512);
    hipMemsetAsync(deg, 0, (size_t)NG * 4, stream);
    hipMemsetAsync(cnt, 0, (size_t)NG * 4, stream);
    hipLaunchKernelGGL(degree_kernel, dim3((NE + 255) / 256), dim3(256), 0, stream, recv, deg, NE);
    hipLaunchKernelGGL(scan_kernel, dim3(1), dim3(1024), 0, stream, deg, csr_off);
    hipLaunchKernelGGL(scatter_kernel, dim3((NE + 255) / 256), dim3(256), 0, stream,
                       recv, csr_off, cnt, csr_edge, NE);

    // 3) edge MLP layer1: H1 = relu(attr @ emlp_w1 + b1) -> bufA
    hipLaunchKernelGGL(edge_l1_kernel, dim3(NE * 512 / 256), dim3(256), 0, stream,
                       attr, emlp_w1, emlp_b1, bufA, NE);
    // 4) T2 = H1 @ emlp_w2 + b2 -> bufB
    hipLaunchKernelGGL(gemm_bt_kernel<1>, dim3(4, NE / 128), dim3(256), 0, stream,
                       bufA, emlp_w2T, emlp_b2, bufB, NE, 512, 512);
    // 5) edges_emb = LN(T2)*g+b (in place, bufB)
    hipLaunchKernelGGL((ln_kernel<0, 512>), dim3(NE / 4), dim3(256), 0, stream,
                       bufB, emlp_g, emlp_be, bufB, (float*)nullptr, (const float*)nullptr, NE);

    // 6) grid_proj = grid_bf @ ge_w1[0:512] -> bufC
    hipLaunchKernelGGL(gemm_bt_kernel<0>, dim3(4, NG / 128), dim3(256), 0, stream,
                       grid_bf, geA_T, (const float*)nullptr, bufC, NG, 512, 512);
    // 7) mesh_proj = mesh_bf @ ge_w1[512:1024] -> bufD
    hipLaunchKernelGGL(gemm_bt_kernel<0>, dim3(4, (NM + 127) / 128), dim3(256), 0, stream,
                       mesh_bf, geB_T, (const float*)nullptr, bufD, NM, 512, 512);
    // 8) T3 = edges_emb @ ge_w1[1024:1536] -> bufA
    hipLaunchKernelGGL(gemm_bt_kernel<0>, dim3(4, NE / 128), dim3(256), 0, stream,
                       bufB, geC_T, (const float*)nullptr, bufA, NE, 512, 512);
    // 9) H2 = relu(T3 + grid_proj[recv] + mesh_proj[send] + ge_b1) (in place, bufA)
    hipLaunchKernelGGL(edge_combine_kernel, dim3(NE * 64 / 256), dim3(256), 0, stream,
                       bufA, bufC, bufD, ge_b1, send, recv, NE);
    // 10) T5 = H2 @ ge_w2 + b2 -> bufB
    hipLaunchKernelGGL(gemm_bt_kernel<1>, dim3(4, NE / 128), dim3(256), 0, stream,
                       bufA, ge_w2T, ge_b2, bufB, NE, 512, 512);
    // 11) msg LN stats only (mu, rs per edge row)
    hipLaunchKernelGGL(ln_stats_kernel, dim3(NE / 4), dim3(256), 0, stream, bufB, stats, NE);
    // 12) X2 = cat(grid_bf, segment_sum(LN(T5))) -> bufA (CSR gather, affine applied on the fly)
    hipLaunchKernelGGL(aggregate_kernel, dim3(NG / 4), dim3(256), 0, stream,
                       bufB, stats, ge_g, ge_be, grid_bf, csr_off, csr_edge, bufA, NG);

    // 13) H3 = relu(X2 @ gn_w1 + b1) -> bufC
    hipLaunchKernelGGL(gemm_bt_kernel<2>, dim3(4, NG / 128), dim3(256), 0, stream,
                       bufA, gn_w1T, gn_b1, bufC, NG, 512, 1024);
    // 14) T8 = H3 @ gn_w2 + b2 -> bufB
    hipLaunchKernelGGL(gemm_bt_kernel<1>, dim3(4, NG / 128), dim3(256), 0, stream,
                       bufC, gn_w2T, gn_b2, bufB, NG, 512, 512);
    // 15) latent = grid + LN(T8)*g+b -> bufA (bf16)
    hipLaunchKernelGGL((ln_kernel<2, 512>), dim3(NG / 4), dim3(256), 0, stream,
                       bufB, gn_g, gn_be, bufA, (float*)nullptr, grid, NG);

    // 16) H4 = relu(latent @ fin_w1 + b1) -> bufC
    hipLaunchKernelGGL(gemm_bt_kernel<2>, dim3(4, NG / 128), dim3(256), 0, stream,
                       bufA, fin_w1T, fin_b1, bufC, NG, 512, 512);
    // 17) T11 = H4 @ fin_w2 + b2 -> bufB  [N=128]
    hipLaunchKernelGGL(gemm_bt_kernel<1>, dim3(1, NG / 128), dim3(256), 0, stream,
                       bufC, fin_w2T, fin_b2, bufB, NG, 128, 512);
    // 18) out = LN(T11)*g+b -> d_out (f32)
    hipLaunchKernelGGL((ln_kernel<3, 128>), dim3(NG / 4), dim3(256), 0, stream,
                       bufB, fin_g, fin_be, (bf16*)nullptr, (float*)d_out, (const float*)nullptr, NG);
}

// Round 4
// 422.546 us; speedup vs baseline: 2.9507x; 1.0649x over previous
//
#include <hip/hip_runtime.h>
#include <hip/hip_bf16.h>
#include <stdint.h>

#define LN_EPS 1e-5f

typedef __hip_bfloat16 bf16;
typedef short short8 __attribute__((ext_vector_type(8)));
typedef float f32x4 __attribute__((ext_vector_type(4)));

static __device__ __forceinline__ float bf2f(short s) {
    unsigned int u = ((unsigned int)(unsigned short)s) << 16;
    return __uint_as_float(u);
}
static __device__ __forceinline__ short f2bf(float x) {
    __hip_bfloat16 h = __float2bfloat16(x);
    return *reinterpret_cast<short*>(&h);
}

// async global->LDS, 16B per lane; LDS dest = wave-uniform base + lane*16
static __device__ __forceinline__ void gload16(const void* g, void* l) {
    __builtin_amdgcn_global_load_lds((const __attribute__((address_space(1))) void*)g,
                                     (__attribute__((address_space(3))) void*)l, 16, 0, 0);
}

// ---------------- weight transpose + bf16 convert ----------------
struct TDesc { const float* src; bf16* dst; int K; int N; int kOff; };
struct TDescs { TDesc d[9]; };

__global__ void transpose_all_kernel(TDescs descs) {
    TDesc t = descs.d[blockIdx.z];
    int kb = blockIdx.x * 32, nb = blockIdx.y * 32;
    if (kb >= t.K || nb >= t.N) return;
    __shared__ float tile[32][33];
    int tx = threadIdx.x & 31, ty = threadIdx.x >> 5;
    for (int i = ty; i < 32; i += 8) {
        int k = kb + i, n = nb + tx;
        tile[i][tx] = (k < t.K && n < t.N) ? t.src[(size_t)(t.kOff + k) * t.N + n] : 0.f;
    }
    __syncthreads();
    for (int i = ty; i < 32; i += 8) {
        int n = nb + i, k = kb + tx;
        if (n < t.N && k < t.K)
            t.dst[(size_t)n * t.K + k] = __float2bfloat16(tile[tx][i]);
    }
}

// ---------------- f32 -> bf16 convert ----------------
__global__ void cvt_bf16_kernel(const float* __restrict__ src, bf16* __restrict__ dst, int n) {
    int i = blockIdx.x * 256 + threadIdx.x;
    int idx = i * 4;
    if (idx >= n) return;
    float4 v = *(const float4*)(src + idx);
    dst[idx + 0] = __float2bfloat16(v.x);
    dst[idx + 1] = __float2bfloat16(v.y);
    dst[idx + 2] = __float2bfloat16(v.z);
    dst[idx + 3] = __float2bfloat16(v.w);
}

// ---------------- edge MLP layer 1 (K=4, fp32) ----------------
__global__ void edge_l1_kernel(const float* __restrict__ attr, const float* __restrict__ w1,
                               const float* __restrict__ b1, bf16* __restrict__ h1, int E) {
    int idx = blockIdx.x * 256 + threadIdx.x;
    if (idx >= E * 512) return;
    int e = idx >> 9, d = idx & 511;
    float4 a = *(const float4*)(attr + (size_t)e * 4);
    float s = a.x * w1[d] + a.y * w1[512 + d] + a.z * w1[1024 + d] + a.w * w1[1536 + d] + b1[d];
    h1[idx] = __float2bfloat16(fmaxf(s, 0.f));
}

// ---------------- bf16 MFMA GEMM: C[M,N] = A[M,K] * BT[N,K]^T ----------------
// m97 single-buffer structure + T2 XOR swizzle (16B-unit ^= row&7) applied as
// pre-swizzled GLOBAL source (linear LDS dest for global_load_lds) + swizzled
// ds_read addresses. XCD-bijective block swizzle. launch_bounds(256,4) for TLP.
// EPI: 0 = none, 1 = +bias, 2 = +bias+relu.  Output bf16.
template <int EPI>
__global__ __launch_bounds__(256, 4) void gemm_bt_kernel(
    const bf16* __restrict__ A, const bf16* __restrict__ BT,
    const float* __restrict__ bias, bf16* __restrict__ C, int M, int N, int K) {
    __shared__ short As[128 * 64];
    __shared__ short Bs[128 * 64];
    const int t = threadIdx.x;
    const int lane = t & 63, w = t >> 6;
    const int wm = w >> 1, wn = w & 1;
    const int lr = lane & 15, lh = lane >> 4;

    // bijective XCD swizzle (m204)
    int nwg = gridDim.x * gridDim.y;
    int orig = blockIdx.y * gridDim.x + blockIdx.x;
    int q = nwg >> 3, r = nwg & 7;
    int xcd = orig & 7, loc = orig >> 3;
    int wg = (xcd < r ? xcd * (q + 1) : r * (q + 1) + (xcd - r) * q) + loc;
    int bx = wg % gridDim.x, by = wg / gridDim.x;
    const int row0 = by * 128;
    const int col0 = bx * 128;

    // staging: wave w covers rows [w*32, w*32+32); instr i adds 8 rows.
    // LDS dest is LINEAR (base + lane*16): physical row = w*32+i*8+(lane>>3),
    // physical 16B-unit = lane&7. Pre-swizzle the GLOBAL column so that
    // physical unit u holds logical unit u ^ (row&7).
    const int sr3 = lane >> 3;                 // row&7 within 8-row group
    const int su = (lane & 7) ^ sr3;           // swizzled global 16B-unit
    const int srow = w * 32 + sr3;
    const int scol = su * 8;                   // in shorts
    const bf16* gaP[4];
    const bf16* gbP[4];
#pragma unroll
    for (int i = 0; i < 4; i++) {
        int ra = row0 + srow + i * 8; if (ra >= M) ra = M - 1;
        int rb = col0 + srow + i * 8; if (rb >= N) rb = N - 1;
        gaP[i] = A + (size_t)ra * K + scol;
        gbP[i] = BT + (size_t)rb * K + scol;
    }

    f32x4 acc[4][4];
#pragma unroll
    for (int i = 0; i < 4; i++)
#pragma unroll
        for (int j = 0; j < 4; j++) acc[i][j] = {0.f, 0.f, 0.f, 0.f};

    for (int k0 = 0; k0 < K; k0 += 64) {
#pragma unroll
        for (int i = 0; i < 4; i++) {
            gload16(gaP[i] + k0, As + (w * 32 + i * 8) * 64);
            gload16(gbP[i] + k0, Bs + (w * 32 + i * 8) * 64);
        }
        __syncthreads();
#pragma unroll
        for (int kk = 0; kk < 64; kk += 32) {
            short8 af[4], bfv[4];
#pragma unroll
            for (int mf = 0; mf < 4; mf++) {
                int rowa = wm * 64 + mf * 16 + lr;
                int ua = ((kk >> 3) + lh) ^ (rowa & 7);     // swizzled 16B-unit
                af[mf] = *(const short8*)&As[rowa * 64 + ua * 8];
            }
#pragma unroll
            for (int nf = 0; nf < 4; nf++) {
                int rowb = wn * 64 + nf * 16 + lr;
                int ub = ((kk >> 3) + lh) ^ (rowb & 7);
                bfv[nf] = *(const short8*)&Bs[rowb * 64 + ub * 8];
            }
#pragma unroll
            for (int mf = 0; mf < 4; mf++)
#pragma unroll
                for (int nf = 0; nf < 4; nf++)
                    acc[mf][nf] = __builtin_amdgcn_mfma_f32_16x16x32_bf16(
                        af[mf], bfv[nf], acc[mf][nf], 0, 0, 0);
        }
        __syncthreads();
    }

#pragma unroll
    for (int nf = 0; nf < 4; nf++) {
        int col = col0 + wn * 64 + nf * 16 + lr;
        float bv = (EPI >= 1) ? bias[col] : 0.f;
#pragma unroll
        for (int mf = 0; mf < 4; mf++) {
#pragma unroll
            for (int r2 = 0; r2 < 4; r2++) {
                int row = row0 + wm * 64 + mf * 16 + lh * 4 + r2;
                if (row < M && col < N) {
                    float v = acc[mf][nf][r2] + bv;
                    if (EPI == 2) v = fmaxf(v, 0.f);
                    C[(size_t)row * N + col] = __float2bfloat16(v);
                }
            }
        }
    }
}

// ---------------- per-edge combine: H2 = relu(T3 + grid_proj[recv] + mesh_proj[send] + b1) ----------------
__global__ void edge_combine_kernel(bf16* __restrict__ T3, const bf16* __restrict__ gridp,
                                    const bf16* __restrict__ meshp, const float* __restrict__ b1,
                                    const int* __restrict__ send, const int* __restrict__ recv, int E) {
    int idx = blockIdx.x * 256 + threadIdx.x;
    if (idx >= E * 64) return;
    int e = idx >> 6;
    int d0 = (idx & 63) * 8;
    int sn = send[e], rn = recv[e];
    short8 tv = *(const short8*)(T3 + (size_t)e * 512 + d0);
    short8 gp = *(const short8*)(gridp + (size_t)rn * 512 + d0);
    short8 mp = *(const short8*)(meshp + (size_t)sn * 512 + d0);
    float4 bA = *(const float4*)(b1 + d0);
    float4 bB = *(const float4*)(b1 + d0 + 4);
    float bb[8] = {bA.x, bA.y, bA.z, bA.w, bB.x, bB.y, bB.z, bB.w};
    short8 o;
#pragma unroll
    for (int j = 0; j < 8; j++)
        o[j] = f2bf(fmaxf(bf2f(tv[j]) + bf2f(gp[j]) + bf2f(mp[j]) + bb[j], 0.f));
    *(short8*)(T3 + (size_t)e * 512 + d0) = o;
}

// ---------------- LayerNorm family: one wave per row ----------------
// MODE 0: out bf16 = LN(x)*g+b           (DN=512)
// MODE 2: out bf16 = resid_f32 + LN(x)*g+b (DN=512)
// MODE 3: out f32 = LN(x)*g+b            (DN=128)
template <int MODE, int DN>
__global__ void ln_kernel(const bf16* __restrict__ X, const float* __restrict__ gw,
                          const float* __restrict__ bw, bf16* __restrict__ outb,
                          float* __restrict__ outf, const float* __restrict__ resid, int R) {
    constexpr int EPL = DN / 64;
    int row = blockIdx.x * 4 + (threadIdx.x >> 6);
    if (row >= R) return;
    int lane = threadIdx.x & 63;
    const bf16* xr = X + (size_t)row * DN + lane * EPL;
    float v[EPL];
    if constexpr (EPL == 8) {
        short8 t8 = *(const short8*)xr;
#pragma unroll
        for (int j = 0; j < 8; j++) v[j] = bf2f(t8[j]);
    } else {
#pragma unroll
        for (int j = 0; j < EPL; j++) v[j] = __bfloat162float(xr[j]);
    }
    float s = 0.f, s2 = 0.f;
#pragma unroll
    for (int j = 0; j < EPL; j++) { s += v[j]; s2 += v[j] * v[j]; }
#pragma unroll
    for (int o = 32; o > 0; o >>= 1) {
        s += __shfl_xor(s, o, 64);
        s2 += __shfl_xor(s2, o, 64);
    }
    float mu = s * (1.f / DN);
    float var = s2 * (1.f / DN) - mu * mu;
    float rs = rsqrtf(var + LN_EPS);
    int d0 = lane * EPL;

    if constexpr (MODE == 0) {
        short8 o;
#pragma unroll
        for (int j = 0; j < EPL; j++)
            o[j] = f2bf((v[j] - mu) * rs * gw[d0 + j] + bw[d0 + j]);
        *(short8*)(outb + (size_t)row * DN + d0) = o;
    } else if constexpr (MODE == 2) {
        short8 o;
#pragma unroll
        for (int j = 0; j < EPL; j++) {
            float y = (v[j] - mu) * rs * gw[d0 + j] + bw[d0 + j];
            o[j] = f2bf(resid[(size_t)row * DN + d0 + j] + y);
        }
        *(short8*)(outb + (size_t)row * DN + d0) = o;
    } else {
#pragma unroll
        for (int j = 0; j < EPL; j++)
            outf[(size_t)row * DN + d0 + j] = (v[j] - mu) * rs * gw[d0 + j] + bw[d0 + j];
    }
}

// ---------------- LN stats only: stats[row] = {mu, rsqrt(var+eps)} (DN=512) ----------------
__global__ void ln_stats_kernel(const bf16* __restrict__ X, float2* __restrict__ stats, int R) {
    int row = blockIdx.x * 4 + (threadIdx.x >> 6);
    if (row >= R) return;
    int lane = threadIdx.x & 63;
    short8 t8 = *(const short8*)(X + (size_t)row * 512 + lane * 8);
    float s = 0.f, s2 = 0.f;
#pragma unroll
    for (int j = 0; j < 8; j++) {
        float x = bf2f(t8[j]);
        s += x; s2 += x * x;
    }
#pragma unroll
    for (int o = 32; o > 0; o >>= 1) {
        s += __shfl_xor(s, o, 64);
        s2 += __shfl_xor(s2, o, 64);
    }
    float mu = s * (1.f / 512.f);
    float var = s2 * (1.f / 512.f) - mu * mu;
    if (lane == 0) stats[row] = make_float2(mu, rsqrtf(var + LN_EPS));
}

// ---------------- CSR build ----------------
__global__ void degree_kernel(const int* __restrict__ recv, int* __restrict__ deg, int E) {
    int e = blockIdx.x * 256 + threadIdx.x;
    if (e < E) atomicAdd(&deg[recv[e]], 1);
}

__global__ void scan_kernel(const int* __restrict__ deg, int* __restrict__ off) {
    __shared__ int partial[1024];
    int t = threadIdx.x;
    int base = t * 16;
    int v[16];
    int s = 0;
#pragma unroll
    for (int i = 0; i < 16; i++) { v[i] = deg[base + i]; s += v[i]; }
    partial[t] = s;
    __syncthreads();
    for (int o = 1; o < 1024; o <<= 1) {
        int x = (t >= o) ? partial[t - o] : 0;
        __syncthreads();
        partial[t] += x;
        __syncthreads();
    }
    int run = (t == 0) ? 0 : partial[t - 1];
#pragma unroll
    for (int i = 0; i < 16; i++) { off[base + i] = run; run += v[i]; }
    if (t == 1023) off[16384] = run;
}

__global__ void scatter_kernel(const int* __restrict__ recv, const int* __restrict__ off,
                               int* __restrict__ cnt, int* __restrict__ edges, int E) {
    int e = blockIdx.x * 256 + threadIdx.x;
    if (e < E) {
        int r = recv[e];
        int p = atomicAdd(&cnt[r], 1);
        edges[off[r] + p] = e;
    }
}

// ---------------- aggregate LN(msg) by receiver + build X2 = cat(grid_bf, aggr) ----------------
__global__ void aggregate_kernel(const bf16* __restrict__ T5, const float2* __restrict__ stats,
                                 const float* __restrict__ gw, const float* __restrict__ bw,
                                 const bf16* __restrict__ gridb,
                                 const int* __restrict__ off, const int* __restrict__ edges,
                                 bf16* __restrict__ X2, int G) {
    int g = blockIdx.x * 4 + (threadIdx.x >> 6);
    if (g >= G) return;
    int lane = threadIdx.x & 63;
    int d0 = lane * 8;
    float gg[8], bb[8];
    {
        float4 a = *(const float4*)(gw + d0), b = *(const float4*)(gw + d0 + 4);
        gg[0]=a.x; gg[1]=a.y; gg[2]=a.z; gg[3]=a.w; gg[4]=b.x; gg[5]=b.y; gg[6]=b.z; gg[7]=b.w;
        float4 c = *(const float4*)(bw + d0), d = *(const float4*)(bw + d0 + 4);
        bb[0]=c.x; bb[1]=c.y; bb[2]=c.z; bb[3]=c.w; bb[4]=d.x; bb[5]=d.y; bb[6]=d.z; bb[7]=d.w;
    }
    float s[8] = {0.f, 0.f, 0.f, 0.f, 0.f, 0.f, 0.f, 0.f};
    int a = off[g], b = off[g + 1];
    for (int i = a; i < b; i++) {
        int e = edges[i];
        float2 st = stats[e];
        short8 m = *(const short8*)(T5 + (size_t)e * 512 + d0);
#pragma unroll
        for (int j = 0; j < 8; j++)
            s[j] += (bf2f(m[j]) - st.x) * st.y * gg[j] + bb[j];
    }
    *(short8*)(X2 + (size_t)g * 1024 + d0) = *(const short8*)(gridb + (size_t)g * 512 + d0);
    short8 o;
#pragma unroll
    for (int j = 0; j < 8; j++) o[j] = f2bf(s[j]);
    *(short8*)(X2 + (size_t)g * 1024 + 512 + d0) = o;
}

extern "C" void kernel_launch(void* const* d_in, const int* in_sizes, int n_in,
                              void* d_out, int out_size, void* d_ws, size_t ws_size,
                              hipStream_t stream) {
    const int NM = 2562, NG = 16384, NE = 49152;
    const float* mesh   = (const float*)d_in[0];
    const float* grid   = (const float*)d_in[1];
    const float* attr   = (const float*)d_in[2];
    const int*   eidx   = (const int*)d_in[3];
    const int*   send   = eidx;
    const int*   recv   = eidx + NE;
    const float* emlp_w1 = (const float*)d_in[4];
    const float* emlp_b1 = (const float*)d_in[5];
    const float* emlp_w2 = (const float*)d_in[6];
    const float* emlp_b2 = (const float*)d_in[7];
    const float* emlp_g  = (const float*)d_in[8];
    const float* emlp_be = (const float*)d_in[9];
    const float* ge_w1 = (const float*)d_in[10];
    const float* ge_b1 = (const float*)d_in[11];
    const float* ge_w2 = (const float*)d_in[12];
    const float* ge_b2 = (const float*)d_in[13];
    const float* ge_g  = (const float*)d_in[14];
    const float* ge_be = (const float*)d_in[15];
    const float* gn_w1 = (const float*)d_in[16];
    const float* gn_b1 = (const float*)d_in[17];
    const float* gn_w2 = (const float*)d_in[18];
    const float* gn_b2 = (const float*)d_in[19];
    const float* gn_g  = (const float*)d_in[20];
    const float* gn_be = (const float*)d_in[21];
    const float* fin_w1 = (const float*)d_in[22];
    const float* fin_b1 = (const float*)d_in[23];
    const float* fin_w2 = (const float*)d_in[24];
    const float* fin_b2 = (const float*)d_in[25];
    const float* fin_g  = (const float*)d_in[26];
    const float* fin_be = (const float*)d_in[27];

    char* p = (char*)d_ws;
    auto take = [&](size_t bytes) -> char* {
        char* r = p;
        p += (bytes + 255) & ~(size_t)255;
        return r;
    };
    bf16* emlp_w2T = (bf16*)take((size_t)512 * 512 * 2);
    bf16* geA_T    = (bf16*)take((size_t)512 * 512 * 2);
    bf16* geB_T    = (bf16*)take((size_t)512 * 512 * 2);
    bf16* geC_T    = (bf16*)take((size_t)512 * 512 * 2);
    bf16* ge_w2T   = (bf16*)take((size_t)512 * 512 * 2);
    bf16* gn_w1T   = (bf16*)take((size_t)512 * 1024 * 2);
    bf16* gn_w2T   = (bf16*)take((size_t)512 * 512 * 2);
    bf16* fin_w1T  = (bf16*)take((size_t)512 * 512 * 2);
    bf16* fin_w2T  = (bf16*)take((size_t)128 * 512 * 2);
    bf16* grid_bf  = (bf16*)take((size_t)NG * 512 * 2);
    bf16* mesh_bf  = (bf16*)take((size_t)NM * 512 * 2);
    bf16* bufA     = (bf16*)take((size_t)NE * 512 * 2);  // H1 -> T3/H2 -> X2 -> latent
    bf16* bufB     = (bf16*)take((size_t)NE * 512 * 2);  // T2/edges_emb -> T5 -> T8 -> T11
    bf16* bufC     = (bf16*)take((size_t)NG * 512 * 2);  // grid_proj -> H3 -> H4
    bf16* bufD     = (bf16*)take((size_t)NM * 512 * 2);  // mesh_proj
    float2* stats  = (float2*)take((size_t)NE * 8);
    int*  deg      = (int*)take((size_t)NG * 4);
    int*  cnt      = (int*)take((size_t)NG * 4);
    int*  csr_off  = (int*)take((size_t)(NG + 1) * 4);
    int*  csr_edge = (int*)take((size_t)NE * 4);

    // 1) transpose + bf16-convert all GEMM weights
    TDescs td;
    td.d[0] = {emlp_w2, emlp_w2T, 512, 512, 0};
    td.d[1] = {ge_w1,   geA_T,    512, 512, 0};
    td.d[2] = {ge_w1,   geB_T,    512, 512, 512};
    td.d[3] = {ge_w1,   geC_T,    512, 512, 1024};
    td.d[4] = {ge_w2,   ge_w2T,   512, 512, 0};
    td.d[5] = {gn_w1,   gn_w1T,  1024, 512, 0};
    td.d[6] = {gn_w2,   gn_w2T,   512, 512, 0};
    td.d[7] = {fin_w1,  fin_w1T,  512, 512, 0};
    td.d[8] = {fin_w2,  fin_w2T,  512, 128, 0};
    hipLaunchKernelGGL(transpose_all_kernel, dim3(32, 16, 9), dim3(256), 0, stream, td);

    // 2) bf16 inputs + CSR build (independent of MLP pipeline)
    hipLaunchKernelGGL(cvt_bf16_kernel, dim3((NG * 512 / 4 + 255) / 256), dim3(256), 0, stream,
                       grid, grid_bf, NG * 512);
    hipLaunchKernelGGL(cvt_bf16_kernel, dim3((NM * 512 / 4 + 255) / 256), dim3(256), 0, stream,
                       mesh, mesh_bf, NM * 512);
    hipMemsetAsync(deg, 0, (size_t)NG * 4, stream);
    hipMemsetAsync(cnt, 0, (size_t)NG * 4, stream);
    hipLaunchKernelGGL(degree_kernel, dim3((NE + 255) / 256), dim3(256), 0, stream, recv, deg, NE);
    hipLaunchKernelGGL(scan_kernel, dim3(1), dim3(1024), 0, stream, deg, csr_off);
    hipLaunchKernelGGL(scatter_kernel, dim3((NE + 255) / 256), dim3(256), 0, stream,
                       recv, csr_off, cnt, csr_edge, NE);

    // 3) edge MLP layer1: H1 = relu(attr @ emlp_w1 + b1) -> bufA
    hipLaunchKernelGGL(edge_l1_kernel, dim3(NE * 512 / 256), dim3(256), 0, stream,
                       attr, emlp_w1, emlp_b1, bufA, NE);
    // 4) T2 = H1 @ emlp_w2 + b2 -> bufB
    hipLaunchKernelGGL(gemm_bt_kernel<1>, dim3(4, NE / 128), dim3(256), 0, stream,
                       bufA, emlp_w2T, emlp_b2, bufB, NE, 512, 512);
    // 5) edges_emb = LN(T2)*g+b (in place, bufB)
    hipLaunchKernelGGL((ln_kernel<0, 512>), dim3(NE / 4), dim3(256), 0, stream,
                       bufB, emlp_g, emlp_be, bufB, (float*)nullptr, (const float*)nullptr, NE);

    // 6) grid_proj = grid_bf @ ge_w1[0:512] -> bufC
    hipLaunchKernelGGL(gemm_bt_kernel<0>, dim3(4, NG / 128), dim3(256), 0, stream,
                       grid_bf, geA_T, (const float*)nullptr, bufC, NG, 512, 512);
    // 7) mesh_proj = mesh_bf @ ge_w1[512:1024] -> bufD
    hipLaunchKernelGGL(gemm_bt_kernel<0>, dim3(4, (NM + 127) / 128), dim3(256), 0, stream,
                       mesh_bf, geB_T, (const float*)nullptr, bufD, NM, 512, 512);
    // 8) T3 = edges_emb @ ge_w1[1024:1536] -> bufA
    hipLaunchKernelGGL(gemm_bt_kernel<0>, dim3(4, NE / 128), dim3(256), 0, stream,
                       bufB, geC_T, (const float*)nullptr, bufA, NE, 512, 512);
    // 9) H2 = relu(T3 + grid_proj[recv] + mesh_proj[send] + ge_b1) (in place, bufA)
    hipLaunchKernelGGL(edge_combine_kernel, dim3(NE * 64 / 256), dim3(256), 0, stream,
                       bufA, bufC, bufD, ge_b1, send, recv, NE);
    // 10) T5 = H2 @ ge_w2 + b2 -> bufB
    hipLaunchKernelGGL(gemm_bt_kernel<1>, dim3(4, NE / 128), dim3(256), 0, stream,
                       bufA, ge_w2T, ge_b2, bufB, NE, 512, 512);
    // 11) msg LN stats only (mu, rs per edge row)
    hipLaunchKernelGGL(ln_stats_kernel, dim3(NE / 4), dim3(256), 0, stream, bufB, stats, NE);
    // 12) X2 = cat(grid_bf, segment_sum(LN(T5))) -> bufA (CSR gather, affine applied on the fly)
    hipLaunchKernelGGL(aggregate_kernel, dim3(NG / 4), dim3(256), 0, stream,
                       bufB, stats, ge_g, ge_be, grid_bf, csr_off, csr_edge, bufA, NG);

    // 13) H3 = relu(X2 @ gn_w1 + b1) -> bufC
    hipLaunchKernelGGL(gemm_bt_kernel<2>, dim3(4, NG / 128), dim3(256), 0, stream,
                       bufA, gn_w1T, gn_b1, bufC, NG, 512, 1024);
    // 14) T8 = H3 @ gn_w2 + b2 -> bufB
    hipLaunchKernelGGL(gemm_bt_kernel<1>, dim3(4, NG / 128), dim3(256), 0, stream,
                       bufC, gn_w2T, gn_b2, bufB, NG, 512, 512);
    // 15) latent = grid + LN(T8)*g+b -> bufA (bf16)
    hipLaunchKernelGGL((ln_kernel<2, 512>), dim3(NG / 4), dim3(256), 0, stream,
                       bufB, gn_g, gn_be, bufA, (float*)nullptr, grid, NG);

    // 16) H4 = relu(latent @ fin_w1 + b1) -> bufC
    hipLaunchKernelGGL(gemm_bt_kernel<2>, dim3(4, NG / 128), dim3(256), 0, stream,
                       bufA, fin_w1T, fin_b1, bufC, NG, 512, 512);
    // 17) T11 = H4 @ fin_w2 + b2 -> bufB  [N=128]
    hipLaunchKernelGGL(gemm_bt_kernel<1>, dim3(1, NG / 128), dim3(256), 0, stream,
                       bufC, fin_w2T, fin_b2, bufB, NG, 128, 512);
    // 18) out = LN(T11)*g+b -> d_out (f32)
    hipLaunchKernelGGL((ln_kernel<3, 128>), dim3(NG / 4), dim3(256), 0, stream,
                       bufB, fin_g, fin_be, (bf16*)nullptr, (float*)d_out, (const float*)nullptr, NG);
}

// Round 5
// 342.229 us; speedup vs baseline: 3.6432x; 1.2347x over previous
//
#include <hip/hip_runtime.h>
#include <hip/hip_bf16.h>
#include <stdint.h>

#define LN_EPS 1e-5f

typedef __hip_bfloat16 bf16;
typedef short short8 __attribute__((ext_vector_type(8)));
typedef float f32x4 __attribute__((ext_vector_type(4)));

static __device__ __forceinline__ float bf2f(short s) {
    unsigned int u = ((unsigned int)(unsigned short)s) << 16;
    return __uint_as_float(u);
}
static __device__ __forceinline__ short f2bf(float x) {
    __hip_bfloat16 h = __float2bfloat16(x);
    return *reinterpret_cast<short*>(&h);
}

// async global->LDS, 16B per lane; LDS dest = wave-uniform base + lane*16
static __device__ __forceinline__ void gload16(const void* g, void* l) {
    __builtin_amdgcn_global_load_lds((const __attribute__((address_space(1))) void*)g,
                                     (__attribute__((address_space(3))) void*)l, 16, 0, 0);
}

// ---------------- weight transpose + bf16 convert ----------------
struct TDesc { const float* src; bf16* dst; int K; int N; int kOff; };
struct TDescs { TDesc d[9]; };

__global__ void transpose_all_kernel(TDescs descs) {
    TDesc t = descs.d[blockIdx.z];
    int kb = blockIdx.x * 32, nb = blockIdx.y * 32;
    if (kb >= t.K || nb >= t.N) return;
    __shared__ float tile[32][33];
    int tx = threadIdx.x & 31, ty = threadIdx.x >> 5;
    for (int i = ty; i < 32; i += 8) {
        int k = kb + i, n = nb + tx;
        tile[i][tx] = (k < t.K && n < t.N) ? t.src[(size_t)(t.kOff + k) * t.N + n] : 0.f;
    }
    __syncthreads();
    for (int i = ty; i < 32; i += 8) {
        int n = nb + i, k = kb + tx;
        if (n < t.N && k < t.K)
            t.dst[(size_t)n * t.K + k] = __float2bfloat16(tile[tx][i]);
    }
}

// ---------------- f32 -> bf16 convert ----------------
__global__ void cvt_bf16_kernel(const float* __restrict__ src, bf16* __restrict__ dst, int n) {
    int i = blockIdx.x * 256 + threadIdx.x;
    int idx = i * 4;
    if (idx >= n) return;
    float4 v = *(const float4*)(src + idx);
    dst[idx + 0] = __float2bfloat16(v.x);
    dst[idx + 1] = __float2bfloat16(v.y);
    dst[idx + 2] = __float2bfloat16(v.z);
    dst[idx + 3] = __float2bfloat16(v.w);
}

// ---------------- edge MLP layer 1: one wave per edge row ----------------
__global__ void edge_l1_kernel(const float* __restrict__ attr, const float* __restrict__ w1,
                               const float* __restrict__ b1, bf16* __restrict__ h1, int E) {
    int e = blockIdx.x * 4 + (threadIdx.x >> 6);
    if (e >= E) return;
    int lane = threadIdx.x & 63;
    int d0 = lane * 8;
    float4 a = *(const float4*)(attr + (size_t)e * 4);
    float av[4] = {a.x, a.y, a.z, a.w};
    float s[8];
    {
        float4 c0 = *(const float4*)(b1 + d0), c1 = *(const float4*)(b1 + d0 + 4);
        s[0]=c0.x; s[1]=c0.y; s[2]=c0.z; s[3]=c0.w; s[4]=c1.x; s[5]=c1.y; s[6]=c1.z; s[7]=c1.w;
    }
#pragma unroll
    for (int k = 0; k < 4; k++) {
        float4 w0 = *(const float4*)(w1 + k * 512 + d0);
        float4 w1v = *(const float4*)(w1 + k * 512 + d0 + 4);
        float wv[8] = {w0.x, w0.y, w0.z, w0.w, w1v.x, w1v.y, w1v.z, w1v.w};
#pragma unroll
        for (int j = 0; j < 8; j++) s[j] += av[k] * wv[j];
    }
    short8 o;
#pragma unroll
    for (int j = 0; j < 8; j++) o[j] = f2bf(fmaxf(s[j], 0.f));
    *(short8*)(h1 + (size_t)e * 512 + d0) = o;
}

// ---------------- bf16 MFMA GEMM: C[M,N] = A[M,K] * BT[N,K]^T ----------------
// m97 single-buffer + T2 XOR swizzle (pre-swizzled global source, linear LDS dest,
// swizzled ds_read). LDS-staged epilogue (stride-66) for full-128B C stores.
// EPI: 0 = none, 1 = +bias, 2 = +bias+relu,
//      3 = +bias + gather(gridp[recv[row]] + meshp[send[row]]) + relu (fused edge combine)
template <int EPI>
__global__ __launch_bounds__(256, 4) void gemm_bt_kernel(
    const bf16* __restrict__ A, const bf16* __restrict__ BT,
    const float* __restrict__ bias, bf16* __restrict__ C, int M, int N, int K,
    const bf16* __restrict__ gridp, const bf16* __restrict__ meshp,
    const int* __restrict__ send, const int* __restrict__ recv) {
    __shared__ short SMEM[2 * 128 * 64];
    short* As = SMEM;
    short* Bs = SMEM + 128 * 64;
    const int t = threadIdx.x;
    const int lane = t & 63, w = t >> 6;
    const int wm = w >> 1, wn = w & 1;
    const int lr = lane & 15, lh = lane >> 4;

    // bijective XCD swizzle (m204)
    int nwg = gridDim.x * gridDim.y;
    int orig = blockIdx.y * gridDim.x + blockIdx.x;
    int q = nwg >> 3, r = nwg & 7;
    int xcd = orig & 7, loc = orig >> 3;
    int wg = (xcd < r ? xcd * (q + 1) : r * (q + 1) + (xcd - r) * q) + loc;
    int bx = wg % gridDim.x, by = wg / gridDim.x;
    const int row0 = by * 128;
    const int col0 = bx * 128;

    // staging: wave w covers rows [w*32, w*32+32); instr i adds 8 rows.
    const int sr3 = lane >> 3;                 // row&7 within 8-row group
    const int su = (lane & 7) ^ sr3;           // swizzled global 16B-unit
    const int srow = w * 32 + sr3;
    const int scol = su * 8;                   // in shorts
    const bf16* gaP[4];
    const bf16* gbP[4];
#pragma unroll
    for (int i = 0; i < 4; i++) {
        int ra = row0 + srow + i * 8; if (ra >= M) ra = M - 1;
        int rb = col0 + srow + i * 8; if (rb >= N) rb = N - 1;
        gaP[i] = A + (size_t)ra * K + scol;
        gbP[i] = BT + (size_t)rb * K + scol;
    }

    f32x4 acc[4][4];
#pragma unroll
    for (int i = 0; i < 4; i++)
#pragma unroll
        for (int j = 0; j < 4; j++) acc[i][j] = {0.f, 0.f, 0.f, 0.f};

    for (int k0 = 0; k0 < K; k0 += 64) {
#pragma unroll
        for (int i = 0; i < 4; i++) {
            gload16(gaP[i] + k0, As + (w * 32 + i * 8) * 64);
            gload16(gbP[i] + k0, Bs + (w * 32 + i * 8) * 64);
        }
        __syncthreads();
#pragma unroll
        for (int kk = 0; kk < 64; kk += 32) {
            short8 af[4], bfv[4];
#pragma unroll
            for (int mf = 0; mf < 4; mf++) {
                int rowa = wm * 64 + mf * 16 + lr;
                int ua = ((kk >> 3) + lh) ^ (rowa & 7);
                af[mf] = *(const short8*)&As[rowa * 64 + ua * 8];
            }
#pragma unroll
            for (int nf = 0; nf < 4; nf++) {
                int rowb = wn * 64 + nf * 16 + lr;
                int ub = ((kk >> 3) + lh) ^ (rowb & 7);
                bfv[nf] = *(const short8*)&Bs[rowb * 64 + ub * 8];
            }
#pragma unroll
            for (int mf = 0; mf < 4; mf++)
#pragma unroll
                for (int nf = 0; nf < 4; nf++)
                    acc[mf][nf] = __builtin_amdgcn_mfma_f32_16x16x32_bf16(
                        af[mf], bfv[nf], acc[mf][nf], 0, 0, 0);
        }
        __syncthreads();
    }

    // ---- LDS-staged epilogue: per-wave private region, stride 66 shorts ----
    // After the loop's final __syncthreads all LDS reads are done; reuse SMEM.
    short* Cw = SMEM + w * (32 * 66);
    const int rgrp = lane >> 3, u = lane & 7;
#pragma unroll
    for (int hp = 0; hp < 2; hp++) {
#pragma unroll
        for (int mf2 = 0; mf2 < 2; mf2++) {
            int mf = hp * 2 + mf2;
#pragma unroll
            for (int nf = 0; nf < 4; nf++)
#pragma unroll
                for (int r2 = 0; r2 < 4; r2++) {
                    int rl = mf2 * 16 + lh * 4 + r2;
                    Cw[rl * 66 + nf * 16 + lr] = f2bf(acc[mf][nf][r2]);
                }
        }
        // wave-internal lgkmcnt ordering is compiler-inserted
#pragma unroll
        for (int rr = 0; rr < 4; rr++) {
            int rl = rr * 8 + rgrp;
            int grow = row0 + wm * 64 + hp * 32 + rl;
            int gcol = col0 + wn * 64 + u * 8;
            short8 vv = *(const short8*)&Cw[rl * 66 + u * 8];
            float vf[8];
#pragma unroll
            for (int j = 0; j < 8; j++) vf[j] = bf2f(vv[j]);
            if (EPI >= 1) {
                float4 c0 = *(const float4*)(bias + gcol);
                float4 c1 = *(const float4*)(bias + gcol + 4);
                float bb[8] = {c0.x, c0.y, c0.z, c0.w, c1.x, c1.y, c1.z, c1.w};
#pragma unroll
                for (int j = 0; j < 8; j++) vf[j] += bb[j];
            }
            if (EPI == 3) {
                int e = grow < M ? grow : M - 1;
                int rn = recv[e], sn = send[e];
                short8 gp = *(const short8*)(gridp + (size_t)rn * 512 + gcol);
                short8 mp = *(const short8*)(meshp + (size_t)sn * 512 + gcol);
#pragma unroll
                for (int j = 0; j < 8; j++) vf[j] += bf2f(gp[j]) + bf2f(mp[j]);
            }
            if (EPI >= 2) {
#pragma unroll
                for (int j = 0; j < 8; j++) vf[j] = fmaxf(vf[j], 0.f);
            }
            short8 o;
#pragma unroll
            for (int j = 0; j < 8; j++) o[j] = f2bf(vf[j]);
            if (grow < M && gcol < N)
                *(short8*)(C + (size_t)grow * N + gcol) = o;
        }
    }
}

// ---------------- LayerNorm family: one wave per row ----------------
// MODE 0: out bf16 = LN(x)*g+b           (DN=512)
// MODE 2: out bf16 = resid_f32 + LN(x)*g+b (DN=512)
// MODE 3: out f32 = LN(x)*g+b            (DN=128)
template <int MODE, int DN>
__global__ void ln_kernel(const bf16* __restrict__ X, const float* __restrict__ gw,
                          const float* __restrict__ bw, bf16* __restrict__ outb,
                          float* __restrict__ outf, const float* __restrict__ resid, int R) {
    constexpr int EPL = DN / 64;
    int row = blockIdx.x * 4 + (threadIdx.x >> 6);
    if (row >= R) return;
    int lane = threadIdx.x & 63;
    const bf16* xr = X + (size_t)row * DN + lane * EPL;
    float v[EPL];
    if constexpr (EPL == 8) {
        short8 t8 = *(const short8*)xr;
#pragma unroll
        for (int j = 0; j < 8; j++) v[j] = bf2f(t8[j]);
    } else {
#pragma unroll
        for (int j = 0; j < EPL; j++) v[j] = __bfloat162float(xr[j]);
    }
    float s = 0.f, s2 = 0.f;
#pragma unroll
    for (int j = 0; j < EPL; j++) { s += v[j]; s2 += v[j] * v[j]; }
#pragma unroll
    for (int o = 32; o > 0; o >>= 1) {
        s += __shfl_xor(s, o, 64);
        s2 += __shfl_xor(s2, o, 64);
    }
    float mu = s * (1.f / DN);
    float var = s2 * (1.f / DN) - mu * mu;
    float rs = rsqrtf(var + LN_EPS);
    int d0 = lane * EPL;

    if constexpr (MODE == 0) {
        short8 o;
#pragma unroll
        for (int j = 0; j < EPL; j++)
            o[j] = f2bf((v[j] - mu) * rs * gw[d0 + j] + bw[d0 + j]);
        *(short8*)(outb + (size_t)row * DN + d0) = o;
    } else if constexpr (MODE == 2) {
        short8 o;
#pragma unroll
        for (int j = 0; j < EPL; j++) {
            float y = (v[j] - mu) * rs * gw[d0 + j] + bw[d0 + j];
            o[j] = f2bf(resid[(size_t)row * DN + d0 + j] + y);
        }
        *(short8*)(outb + (size_t)row * DN + d0) = o;
    } else {
#pragma unroll
        for (int j = 0; j < EPL; j++)
            outf[(size_t)row * DN + d0 + j] = (v[j] - mu) * rs * gw[d0 + j] + bw[d0 + j];
    }
}

// ---------------- LN stats only: stats[row] = {mu, rsqrt(var+eps)} (DN=512) ----------------
__global__ void ln_stats_kernel(const bf16* __restrict__ X, float2* __restrict__ stats, int R) {
    int row = blockIdx.x * 4 + (threadIdx.x >> 6);
    if (row >= R) return;
    int lane = threadIdx.x & 63;
    short8 t8 = *(const short8*)(X + (size_t)row * 512 + lane * 8);
    float s = 0.f, s2 = 0.f;
#pragma unroll
    for (int j = 0; j < 8; j++) {
        float x = bf2f(t8[j]);
        s += x; s2 += x * x;
    }
#pragma unroll
    for (int o = 32; o > 0; o >>= 1) {
        s += __shfl_xor(s, o, 64);
        s2 += __shfl_xor(s2, o, 64);
    }
    float mu = s * (1.f / 512.f);
    float var = s2 * (1.f / 512.f) - mu * mu;
    if (lane == 0) stats[row] = make_float2(mu, rsqrtf(var + LN_EPS));
}

// ---------------- CSR build ----------------
__global__ void degree_kernel(const int* __restrict__ recv, int* __restrict__ deg, int E) {
    int e = blockIdx.x * 256 + threadIdx.x;
    if (e < E) atomicAdd(&deg[recv[e]], 1);
}

__global__ void scan_kernel(const int* __restrict__ deg, int* __restrict__ off) {
    __shared__ int partial[1024];
    int t = threadIdx.x;
    int base = t * 16;
    int v[16];
    int s = 0;
#pragma unroll
    for (int i = 0; i < 16; i++) { v[i] = deg[base + i]; s += v[i]; }
    partial[t] = s;
    __syncthreads();
    for (int o = 1; o < 1024; o <<= 1) {
        int x = (t >= o) ? partial[t - o] : 0;
        __syncthreads();
        partial[t] += x;
        __syncthreads();
    }
    int run = (t == 0) ? 0 : partial[t - 1];
#pragma unroll
    for (int i = 0; i < 16; i++) { off[base + i] = run; run += v[i]; }
    if (t == 1023) off[16384] = run;
}

__global__ void scatter_kernel(const int* __restrict__ recv, const int* __restrict__ off,
                               int* __restrict__ cnt, int* __restrict__ edges, int E) {
    int e = blockIdx.x * 256 + threadIdx.x;
    if (e < E) {
        int r = recv[e];
        int p = atomicAdd(&cnt[r], 1);
        edges[off[r] + p] = e;
    }
}

// ---------------- aggregate LN(msg) by receiver + build X2 = cat(grid_bf, aggr) ----------------
__global__ void aggregate_kernel(const bf16* __restrict__ T5, const float2* __restrict__ stats,
                                 const float* __restrict__ gw, const float* __restrict__ bw,
                                 const bf16* __restrict__ gridb,
                                 const int* __restrict__ off, const int* __restrict__ edges,
                                 bf16* __restrict__ X2, int G) {
    int g = blockIdx.x * 4 + (threadIdx.x >> 6);
    if (g >= G) return;
    int lane = threadIdx.x & 63;
    int d0 = lane * 8;
    float gg[8], bb[8];
    {
        float4 a = *(const float4*)(gw + d0), b = *(const float4*)(gw + d0 + 4);
        gg[0]=a.x; gg[1]=a.y; gg[2]=a.z; gg[3]=a.w; gg[4]=b.x; gg[5]=b.y; gg[6]=b.z; gg[7]=b.w;
        float4 c = *(const float4*)(bw + d0), d = *(const float4*)(bw + d0 + 4);
        bb[0]=c.x; bb[1]=c.y; bb[2]=c.z; bb[3]=c.w; bb[4]=d.x; bb[5]=d.y; bb[6]=d.z; bb[7]=d.w;
    }
    float s[8] = {0.f, 0.f, 0.f, 0.f, 0.f, 0.f, 0.f, 0.f};
    int a = off[g], b = off[g + 1];
    for (int i = a; i < b; i++) {
        int e = edges[i];
        float2 st = stats[e];
        short8 m = *(const short8*)(T5 + (size_t)e * 512 + d0);
#pragma unroll
        for (int j = 0; j < 8; j++)
            s[j] += (bf2f(m[j]) - st.x) * st.y * gg[j] + bb[j];
    }
    *(short8*)(X2 + (size_t)g * 1024 + d0) = *(const short8*)(gridb + (size_t)g * 512 + d0);
    short8 o;
#pragma unroll
    for (int j = 0; j < 8; j++) o[j] = f2bf(s[j]);
    *(short8*)(X2 + (size_t)g * 1024 + 512 + d0) = o;
}

extern "C" void kernel_launch(void* const* d_in, const int* in_sizes, int n_in,
                              void* d_out, int out_size, void* d_ws, size_t ws_size,
                              hipStream_t stream) {
    const int NM = 2562, NG = 16384, NE = 49152;
    const float* mesh   = (const float*)d_in[0];
    const float* grid   = (const float*)d_in[1];
    const float* attr   = (const float*)d_in[2];
    const int*   eidx   = (const int*)d_in[3];
    const int*   send   = eidx;
    const int*   recv   = eidx + NE;
    const float* emlp_w1 = (const float*)d_in[4];
    const float* emlp_b1 = (const float*)d_in[5];
    const float* emlp_w2 = (const float*)d_in[6];
    const float* emlp_b2 = (const float*)d_in[7];
    const float* emlp_g  = (const float*)d_in[8];
    const float* emlp_be = (const float*)d_in[9];
    const float* ge_w1 = (const float*)d_in[10];
    const float* ge_b1 = (const float*)d_in[11];
    const float* ge_w2 = (const float*)d_in[12];
    const float* ge_b2 = (const float*)d_in[13];
    const float* ge_g  = (const float*)d_in[14];
    const float* ge_be = (const float*)d_in[15];
    const float* gn_w1 = (const float*)d_in[16];
    const float* gn_b1 = (const float*)d_in[17];
    const float* gn_w2 = (const float*)d_in[18];
    const float* gn_b2 = (const float*)d_in[19];
    const float* gn_g  = (const float*)d_in[20];
    const float* gn_be = (const float*)d_in[21];
    const float* fin_w1 = (const float*)d_in[22];
    const float* fin_b1 = (const float*)d_in[23];
    const float* fin_w2 = (const float*)d_in[24];
    const float* fin_b2 = (const float*)d_in[25];
    const float* fin_g  = (const float*)d_in[26];
    const float* fin_be = (const float*)d_in[27];

    char* p = (char*)d_ws;
    auto take = [&](size_t bytes) -> char* {
        char* r = p;
        p += (bytes + 255) & ~(size_t)255;
        return r;
    };
    bf16* emlp_w2T = (bf16*)take((size_t)512 * 512 * 2);
    bf16* geA_T    = (bf16*)take((size_t)512 * 512 * 2);
    bf16* geB_T    = (bf16*)take((size_t)512 * 512 * 2);
    bf16* geC_T    = (bf16*)take((size_t)512 * 512 * 2);
    bf16* ge_w2T   = (bf16*)take((size_t)512 * 512 * 2);
    bf16* gn_w1T   = (bf16*)take((size_t)512 * 1024 * 2);
    bf16* gn_w2T   = (bf16*)take((size_t)512 * 512 * 2);
    bf16* fin_w1T  = (bf16*)take((size_t)512 * 512 * 2);
    bf16* fin_w2T  = (bf16*)take((size_t)128 * 512 * 2);
    bf16* grid_bf  = (bf16*)take((size_t)NG * 512 * 2);
    bf16* mesh_bf  = (bf16*)take((size_t)NM * 512 * 2);
    bf16* bufA     = (bf16*)take((size_t)NE * 512 * 2);  // H1 -> H2 -> X2 -> latent
    bf16* bufB     = (bf16*)take((size_t)NE * 512 * 2);  // T2/edges_emb -> T5 -> T8 -> T11
    bf16* bufC     = (bf16*)take((size_t)NG * 512 * 2);  // grid_proj -> H3 -> H4
    bf16* bufD     = (bf16*)take((size_t)NM * 512 * 2);  // mesh_proj
    float2* stats  = (float2*)take((size_t)NE * 8);
    int*  deg      = (int*)take((size_t)NG * 4);
    int*  cnt      = (int*)take((size_t)NG * 4);
    int*  csr_off  = (int*)take((size_t)(NG + 1) * 4);
    int*  csr_edge = (int*)take((size_t)NE * 4);

    // 1) transpose + bf16-convert all GEMM weights
    TDescs td;
    td.d[0] = {emlp_w2, emlp_w2T, 512, 512, 0};
    td.d[1] = {ge_w1,   geA_T,    512, 512, 0};
    td.d[2] = {ge_w1,   geB_T,    512, 512, 512};
    td.d[3] = {ge_w1,   geC_T,    512, 512, 1024};
    td.d[4] = {ge_w2,   ge_w2T,   512, 512, 0};
    td.d[5] = {gn_w1,   gn_w1T,  1024, 512, 0};
    td.d[6] = {gn_w2,   gn_w2T,   512, 512, 0};
    td.d[7] = {fin_w1,  fin_w1T,  512, 512, 0};
    td.d[8] = {fin_w2,  fin_w2T,  512, 128, 0};
    hipLaunchKernelGGL(transpose_all_kernel, dim3(32, 16, 9), dim3(256), 0, stream, td);

    // 2) bf16 inputs + CSR build (independent of MLP pipeline)
    hipLaunchKernelGGL(cvt_bf16_kernel, dim3((NG * 512 / 4 + 255) / 256), dim3(256), 0, stream,
                       grid, grid_bf, NG * 512);
    hipLaunchKernelGGL(cvt_bf16_kernel, dim3((NM * 512 / 4 + 255) / 256), dim3(256), 0, stream,
                       mesh, mesh_bf, NM * 512);
    hipMemsetAsync(deg, 0, (size_t)NG * 4, stream);
    hipMemsetAsync(cnt, 0, (size_t)NG * 4, stream);
    hipLaunchKernelGGL(degree_kernel, dim3((NE + 255) / 256), dim3(256), 0, stream, recv, deg, NE);
    hipLaunchKernelGGL(scan_kernel, dim3(1), dim3(1024), 0, stream, deg, csr_off);
    hipLaunchKernelGGL(scatter_kernel, dim3((NE + 255) / 256), dim3(256), 0, stream,
                       recv, csr_off, cnt, csr_edge, NE);

    // 3) edge MLP layer1: H1 = relu(attr @ emlp_w1 + b1) -> bufA (wave per row)
    hipLaunchKernelGGL(edge_l1_kernel, dim3(NE / 4), dim3(256), 0, stream,
                       attr, emlp_w1, emlp_b1, bufA, NE);
    // 4) T2 = H1 @ emlp_w2 + b2 -> bufB
    hipLaunchKernelGGL(gemm_bt_kernel<1>, dim3(4, NE / 128), dim3(256), 0, stream,
                       bufA, emlp_w2T, emlp_b2, bufB, NE, 512, 512,
                       (const bf16*)nullptr, (const bf16*)nullptr, (const int*)nullptr, (const int*)nullptr);
    // 5) edges_emb = LN(T2)*g+b (in place, bufB)
    hipLaunchKernelGGL((ln_kernel<0, 512>), dim3(NE / 4), dim3(256), 0, stream,
                       bufB, emlp_g, emlp_be, bufB, (float*)nullptr, (const float*)nullptr, NE);

    // 6) grid_proj = grid_bf @ ge_w1[0:512] -> bufC
    hipLaunchKernelGGL(gemm_bt_kernel<0>, dim3(4, NG / 128), dim3(256), 0, stream,
                       grid_bf, geA_T, (const float*)nullptr, bufC, NG, 512, 512,
                       (const bf16*)nullptr, (const bf16*)nullptr, (const int*)nullptr, (const int*)nullptr);
    // 7) mesh_proj = mesh_bf @ ge_w1[512:1024] -> bufD
    hipLaunchKernelGGL(gemm_bt_kernel<0>, dim3(4, (NM + 127) / 128), dim3(256), 0, stream,
                       mesh_bf, geB_T, (const float*)nullptr, bufD, NM, 512, 512,
                       (const bf16*)nullptr, (const bf16*)nullptr, (const int*)nullptr, (const int*)nullptr);
    // 8+9) H2 = relu(edges_emb @ ge_w1[1024:1536] + grid_proj[recv] + mesh_proj[send] + ge_b1)
    //      fused in GEMM epilogue (EPI=3) -> bufA
    hipLaunchKernelGGL(gemm_bt_kernel<3>, dim3(4, NE / 128), dim3(256), 0, stream,
                       bufB, geC_T, ge_b1, bufA, NE, 512, 512,
                       bufC, bufD, send, recv);
    // 10) T5 = H2 @ ge_w2 + b2 -> bufB
    hipLaunchKernelGGL(gemm_bt_kernel<1>, dim3(4, NE / 128), dim3(256), 0, stream,
                       bufA, ge_w2T, ge_b2, bufB, NE, 512, 512,
                       (const bf16*)nullptr, (const bf16*)nullptr, (const int*)nullptr, (const int*)nullptr);
    // 11) msg LN stats only (mu, rs per edge row)
    hipLaunchKernelGGL(ln_stats_kernel, dim3(NE / 4), dim3(256), 0, stream, bufB, stats, NE);
    // 12) X2 = cat(grid_bf, segment_sum(LN(T5))) -> bufA (CSR gather, affine on the fly)
    hipLaunchKernelGGL(aggregate_kernel, dim3(NG / 4), dim3(256), 0, stream,
                       bufB, stats, ge_g, ge_be, grid_bf, csr_off, csr_edge, bufA, NG);

    // 13) H3 = relu(X2 @ gn_w1 + b1) -> bufC
    hipLaunchKernelGGL(gemm_bt_kernel<2>, dim3(4, NG / 128), dim3(256), 0, stream,
                       bufA, gn_w1T, gn_b1, bufC, NG, 512, 1024,
                       (const bf16*)nullptr, (const bf16*)nullptr, (const int*)nullptr, (const int*)nullptr);
    // 14) T8 = H3 @ gn_w2 + b2 -> bufB
    hipLaunchKernelGGL(gemm_bt_kernel<1>, dim3(4, NG / 128), dim3(256), 0, stream,
                       bufC, gn_w2T, gn_b2, bufB, NG, 512, 512,
                       (const bf16*)nullptr, (const bf16*)nullptr, (const int*)nullptr, (const int*)nullptr);
    // 15) latent = grid + LN(T8)*g+b -> bufA (bf16)
    hipLaunchKernelGGL((ln_kernel<2, 512>), dim3(NG / 4), dim3(256), 0, stream,
                       bufB, gn_g, gn_be, bufA, (float*)nullptr, grid, NG);

    // 16) H4 = relu(latent @ fin_w1 + b1) -> bufC
    hipLaunchKernelGGL(gemm_bt_kernel<2>, dim3(4, NG / 128), dim3(256), 0, stream,
                       bufA, fin_w1T, fin_b1, bufC, NG, 512, 512,
                       (const bf16*)nullptr, (const bf16*)nullptr, (const int*)nullptr, (const int*)nullptr);
    // 17) T11 = H4 @ fin_w2 + b2 -> bufB  [N=128]
    hipLaunchKernelGGL(gemm_bt_kernel<1>, dim3(1, NG / 128), dim3(256), 0, stream,
                       bufC, fin_w2T, fin_b2, bufB, NG, 128, 512,
                       (const bf16*)nullptr, (const bf16*)nullptr, (const int*)nullptr, (const int*)nullptr);
    // 18) out = LN(T11)*g+b -> d_out (f32)
    hipLaunchKernelGGL((ln_kernel<3, 128>), dim3(NG / 4), dim3(256), 0, stream,
                       bufB, fin_g, fin_be, (bf16*)nullptr, (float*)d_out, (const float*)nullptr, NG);
}

// Round 6
// 336.213 us; speedup vs baseline: 3.7084x; 1.0179x over previous
//
#include <hip/hip_runtime.h>
#include <hip/hip_bf16.h>
#include <stdint.h>

#define LN_EPS 1e-5f

typedef __hip_bfloat16 bf16;
typedef short short8 __attribute__((ext_vector_type(8)));
typedef float f32x4 __attribute__((ext_vector_type(4)));

static __device__ __forceinline__ float bf2f(short s) {
    unsigned int u = ((unsigned int)(unsigned short)s) << 16;
    return __uint_as_float(u);
}
static __device__ __forceinline__ short f2bf(float x) {
    __hip_bfloat16 h = __float2bfloat16(x);
    return *reinterpret_cast<short*>(&h);
}

// async global->LDS, 16B per lane; LDS dest = wave-uniform base + lane*16
static __device__ __forceinline__ void gload16(const void* g, void* l) {
    __builtin_amdgcn_global_load_lds((const __attribute__((address_space(1))) void*)g,
                                     (__attribute__((address_space(3))) void*)l, 16, 0, 0);
}

// ---------------- weight transpose + bf16 convert ----------------
struct TDesc { const float* src; bf16* dst; int K; int N; int kOff; };
struct TDescs { TDesc d[9]; };

__global__ void transpose_all_kernel(TDescs descs) {
    TDesc t = descs.d[blockIdx.z];
    int kb = blockIdx.x * 32, nb = blockIdx.y * 32;
    if (kb >= t.K || nb >= t.N) return;
    __shared__ float tile[32][33];
    int tx = threadIdx.x & 31, ty = threadIdx.x >> 5;
    for (int i = ty; i < 32; i += 8) {
        int k = kb + i, n = nb + tx;
        tile[i][tx] = (k < t.K && n < t.N) ? t.src[(size_t)(t.kOff + k) * t.N + n] : 0.f;
    }
    __syncthreads();
    for (int i = ty; i < 32; i += 8) {
        int n = nb + i, k = kb + tx;
        if (n < t.N && k < t.K)
            t.dst[(size_t)n * t.K + k] = __float2bfloat16(tile[tx][i]);
    }
}

// ---------------- f32 -> bf16 convert ----------------
__global__ void cvt_bf16_kernel(const float* __restrict__ src, bf16* __restrict__ dst, int n) {
    int i = blockIdx.x * 256 + threadIdx.x;
    int idx = i * 4;
    if (idx >= n) return;
    float4 v = *(const float4*)(src + idx);
    dst[idx + 0] = __float2bfloat16(v.x);
    dst[idx + 1] = __float2bfloat16(v.y);
    dst[idx + 2] = __float2bfloat16(v.z);
    dst[idx + 3] = __float2bfloat16(v.w);
}

// ---------------- edge MLP layer 1: one wave per edge row ----------------
__global__ void edge_l1_kernel(const float* __restrict__ attr, const float* __restrict__ w1,
                               const float* __restrict__ b1, bf16* __restrict__ h1, int E) {
    int e = blockIdx.x * 4 + (threadIdx.x >> 6);
    if (e >= E) return;
    int lane = threadIdx.x & 63;
    int d0 = lane * 8;
    float4 a = *(const float4*)(attr + (size_t)e * 4);
    float av[4] = {a.x, a.y, a.z, a.w};
    float s[8];
    {
        float4 c0 = *(const float4*)(b1 + d0), c1 = *(const float4*)(b1 + d0 + 4);
        s[0]=c0.x; s[1]=c0.y; s[2]=c0.z; s[3]=c0.w; s[4]=c1.x; s[5]=c1.y; s[6]=c1.z; s[7]=c1.w;
    }
#pragma unroll
    for (int k = 0; k < 4; k++) {
        float4 w0 = *(const float4*)(w1 + k * 512 + d0);
        float4 w1v = *(const float4*)(w1 + k * 512 + d0 + 4);
        float wv[8] = {w0.x, w0.y, w0.z, w0.w, w1v.x, w1v.y, w1v.z, w1v.w};
#pragma unroll
        for (int j = 0; j < 8; j++) s[j] += av[k] * wv[j];
    }
    short8 o;
#pragma unroll
    for (int j = 0; j < 8; j++) o[j] = f2bf(fmaxf(s[j], 0.f));
    *(short8*)(h1 + (size_t)e * 512 + d0) = o;
}

// ---------------- bf16 MFMA GEMM: C[M,N] = A[M,K] * BT[N,K]^T ----------------
// 2-phase prefetch (T3-minimum): dbuf LDS, STAGE(next) issued BEFORE compute(cur),
// one __syncthreads per K-tile (drain lands after MFMA covered the latency).
// T2 XOR swizzle via pre-swizzled global source + swizzled ds_read.
// Panel-grouping XCD swizzle (col-blocks of one A panel share an XCD).
// LDS-staged epilogue for full-128B C stores.
// EPI: 0 = none, 1 = +bias, 2 = +bias+relu,
//      3 = +bias + gather(gridp[recv[row]] + meshp[send[row]]) + relu
template <int EPI>
__global__ __launch_bounds__(256, 2) void gemm_bt_kernel(
    const bf16* __restrict__ A, const bf16* __restrict__ BT,
    const float* __restrict__ bias, bf16* __restrict__ C, int M, int N, int K,
    const bf16* __restrict__ gridp, const bf16* __restrict__ meshp,
    const int* __restrict__ send, const int* __restrict__ recv) {
    __shared__ short SMEM[2 * 2 * 128 * 64];   // [buf][A|B] 64 KB
    const int t = threadIdx.x;
    const int lane = t & 63, w = t >> 6;
    const int wm = w >> 1, wn = w & 1;
    const int lr = lane & 15, lh = lane >> 4;

    // XCD swizzle: keep all col-blocks of an A row-panel on one XCD
    int gx = gridDim.x, gy = gridDim.y;
    int orig = blockIdx.y * gx + blockIdx.x;
    int bx, by;
    if ((gy & 7) == 0) {
        int xcd = orig & 7, t2 = orig >> 3;
        bx = t2 % gx;
        by = xcd + 8 * (t2 / gx);
    } else { bx = blockIdx.x; by = blockIdx.y; }
    const int row0 = by * 128;
    const int col0 = bx * 128;

    // staging: wave w covers rows [w*32, w*32+32); instr i adds 8 rows.
    const int sr3 = lane >> 3;                 // row&7 within 8-row group
    const int su = (lane & 7) ^ sr3;           // pre-swizzled global 16B-unit
    const int srow = w * 32 + sr3;
    const int scol = su * 8;                   // in shorts
    const bf16* gaP[4];
    const bf16* gbP[4];
#pragma unroll
    for (int i = 0; i < 4; i++) {
        int ra = row0 + srow + i * 8; if (ra >= M) ra = M - 1;
        int rb = col0 + srow + i * 8; if (rb >= N) rb = N - 1;
        gaP[i] = A + (size_t)ra * K + scol;
        gbP[i] = BT + (size_t)rb * K + scol;
    }

    auto STAGE = [&](int b, int k0) {
        short* la = SMEM + b * 16384 + w * 32 * 64;
        short* lb = la + 8192;
#pragma unroll
        for (int i = 0; i < 4; i++) {
            gload16(gaP[i] + k0, la + i * 8 * 64);
            gload16(gbP[i] + k0, lb + i * 8 * 64);
        }
    };

    f32x4 acc[4][4];
#pragma unroll
    for (int i = 0; i < 4; i++)
#pragma unroll
        for (int j = 0; j < 4; j++) acc[i][j] = {0.f, 0.f, 0.f, 0.f};

    const int T = K >> 6;
    STAGE(0, 0);
    __syncthreads();

    int cur = 0;
    for (int tt = 0; tt < T; ++tt) {
        if (tt + 1 < T) STAGE(cur ^ 1, (tt + 1) << 6);   // prefetch in flight
        const short* Ac = SMEM + cur * 16384;
        const short* Bc = Ac + 8192;
#pragma unroll
        for (int kk = 0; kk < 64; kk += 32) {
            short8 af[4], bfv[4];
#pragma unroll
            for (int mf = 0; mf < 4; mf++) {
                int rowa = wm * 64 + mf * 16 + lr;
                int ua = ((kk >> 3) + lh) ^ (rowa & 7);
                af[mf] = *(const short8*)&Ac[rowa * 64 + ua * 8];
            }
#pragma unroll
            for (int nf = 0; nf < 4; nf++) {
                int rowb = wn * 64 + nf * 16 + lr;
                int ub = ((kk >> 3) + lh) ^ (rowb & 7);
                bfv[nf] = *(const short8*)&Bc[rowb * 64 + ub * 8];
            }
#pragma unroll
            for (int mf = 0; mf < 4; mf++)
#pragma unroll
                for (int nf = 0; nf < 4; nf++)
                    acc[mf][nf] = __builtin_amdgcn_mfma_f32_16x16x32_bf16(
                        af[mf], bfv[nf], acc[mf][nf], 0, 0, 0);
        }
        __syncthreads();    // drains vmcnt: prefetch had the whole MFMA phase
        cur ^= 1;
    }

    // ---- LDS-staged epilogue: per-wave private region, stride 66 shorts ----
    short* Cw = SMEM + w * (32 * 66);
    const int rgrp = lane >> 3, u = lane & 7;
#pragma unroll
    for (int hp = 0; hp < 2; hp++) {
#pragma unroll
        for (int mf2 = 0; mf2 < 2; mf2++) {
            int mf = hp * 2 + mf2;
#pragma unroll
            for (int nf = 0; nf < 4; nf++)
#pragma unroll
                for (int r2 = 0; r2 < 4; r2++) {
                    int rl = mf2 * 16 + lh * 4 + r2;
                    Cw[rl * 66 + nf * 16 + lr] = f2bf(acc[mf][nf][r2]);
                }
        }
#pragma unroll
        for (int rr = 0; rr < 4; rr++) {
            int rl = rr * 8 + rgrp;
            int grow = row0 + wm * 64 + hp * 32 + rl;
            int gcol = col0 + wn * 64 + u * 8;
            short8 vv = *(const short8*)&Cw[rl * 66 + u * 8];
            float vf[8];
#pragma unroll
            for (int j = 0; j < 8; j++) vf[j] = bf2f(vv[j]);
            if (EPI >= 1) {
                float4 c0 = *(const float4*)(bias + gcol);
                float4 c1 = *(const float4*)(bias + gcol + 4);
                float bb[8] = {c0.x, c0.y, c0.z, c0.w, c1.x, c1.y, c1.z, c1.w};
#pragma unroll
                for (int j = 0; j < 8; j++) vf[j] += bb[j];
            }
            if (EPI == 3) {
                int e = grow < M ? grow : M - 1;
                int rn = recv[e], sn = send[e];
                short8 gp = *(const short8*)(gridp + (size_t)rn * 512 + gcol);
                short8 mp = *(const short8*)(meshp + (size_t)sn * 512 + gcol);
#pragma unroll
                for (int j = 0; j < 8; j++) vf[j] += bf2f(gp[j]) + bf2f(mp[j]);
            }
            if (EPI >= 2) {
#pragma unroll
                for (int j = 0; j < 8; j++) vf[j] = fmaxf(vf[j], 0.f);
            }
            short8 o;
#pragma unroll
            for (int j = 0; j < 8; j++) o[j] = f2bf(vf[j]);
            if (grow < M && gcol < N)
                *(short8*)(C + (size_t)grow * N + gcol) = o;
        }
    }
}

// ---------------- LayerNorm family: one wave per row ----------------
// MODE 0: out bf16 = LN(x)*g+b             (DN=512)
// MODE 2: out bf16 = resid_bf16 + LN(x)*g+b (DN=512)
// MODE 3: out f32 = LN(x)*g+b              (DN=128)
template <int MODE, int DN>
__global__ void ln_kernel(const bf16* __restrict__ X, const float* __restrict__ gw,
                          const float* __restrict__ bw, bf16* __restrict__ outb,
                          float* __restrict__ outf, const bf16* __restrict__ resid, int R) {
    constexpr int EPL = DN / 64;
    int row = blockIdx.x * 4 + (threadIdx.x >> 6);
    if (row >= R) return;
    int lane = threadIdx.x & 63;
    const bf16* xr = X + (size_t)row * DN + lane * EPL;
    float v[EPL];
    if constexpr (EPL == 8) {
        short8 t8 = *(const short8*)xr;
#pragma unroll
        for (int j = 0; j < 8; j++) v[j] = bf2f(t8[j]);
    } else {
#pragma unroll
        for (int j = 0; j < EPL; j++) v[j] = __bfloat162float(xr[j]);
    }
    float s = 0.f, s2 = 0.f;
#pragma unroll
    for (int j = 0; j < EPL; j++) { s += v[j]; s2 += v[j] * v[j]; }
#pragma unroll
    for (int o = 32; o > 0; o >>= 1) {
        s += __shfl_xor(s, o, 64);
        s2 += __shfl_xor(s2, o, 64);
    }
    float mu = s * (1.f / DN);
    float var = s2 * (1.f / DN) - mu * mu;
    float rs = rsqrtf(var + LN_EPS);
    int d0 = lane * EPL;

    if constexpr (MODE == 0) {
        short8 o;
#pragma unroll
        for (int j = 0; j < EPL; j++)
            o[j] = f2bf((v[j] - mu) * rs * gw[d0 + j] + bw[d0 + j]);
        *(short8*)(outb + (size_t)row * DN + d0) = o;
    } else if constexpr (MODE == 2) {
        short8 rv = *(const short8*)(resid + (size_t)row * DN + d0);
        short8 o;
#pragma unroll
        for (int j = 0; j < EPL; j++) {
            float y = (v[j] - mu) * rs * gw[d0 + j] + bw[d0 + j];
            o[j] = f2bf(bf2f(rv[j]) + y);
        }
        *(short8*)(outb + (size_t)row * DN + d0) = o;
    } else {
#pragma unroll
        for (int j = 0; j < EPL; j++)
            outf[(size_t)row * DN + d0 + j] = (v[j] - mu) * rs * gw[d0 + j] + bw[d0 + j];
    }
}

// ---------------- LN stats only: stats[row] = {mu, rsqrt(var+eps)} (DN=512) ----------------
__global__ void ln_stats_kernel(const bf16* __restrict__ X, float2* __restrict__ stats, int R) {
    int row = blockIdx.x * 4 + (threadIdx.x >> 6);
    if (row >= R) return;
    int lane = threadIdx.x & 63;
    short8 t8 = *(const short8*)(X + (size_t)row * 512 + lane * 8);
    float s = 0.f, s2 = 0.f;
#pragma unroll
    for (int j = 0; j < 8; j++) {
        float x = bf2f(t8[j]);
        s += x; s2 += x * x;
    }
#pragma unroll
    for (int o = 32; o > 0; o >>= 1) {
        s += __shfl_xor(s, o, 64);
        s2 += __shfl_xor(s2, o, 64);
    }
    float mu = s * (1.f / 512.f);
    float var = s2 * (1.f / 512.f) - mu * mu;
    if (lane == 0) stats[row] = make_float2(mu, rsqrtf(var + LN_EPS));
}

// ---------------- CSR build ----------------
__global__ void degree_kernel(const int* __restrict__ recv, int* __restrict__ deg, int E) {
    int e = blockIdx.x * 256 + threadIdx.x;
    if (e < E) atomicAdd(&deg[recv[e]], 1);
}

__global__ void scan_kernel(const int* __restrict__ deg, int* __restrict__ off) {
    __shared__ int partial[1024];
    int t = threadIdx.x;
    int base = t * 16;
    int v[16];
    int s = 0;
#pragma unroll
    for (int i = 0; i < 16; i++) { v[i] = deg[base + i]; s += v[i]; }
    partial[t] = s;
    __syncthreads();
    for (int o = 1; o < 1024; o <<= 1) {
        int x = (t >= o) ? partial[t - o] : 0;
        __syncthreads();
        partial[t] += x;
        __syncthreads();
    }
    int run = (t == 0) ? 0 : partial[t - 1];
#pragma unroll
    for (int i = 0; i < 16; i++) { off[base + i] = run; run += v[i]; }
    if (t == 1023) off[16384] = run;
}

__global__ void scatter_kernel(const int* __restrict__ recv, const int* __restrict__ off,
                               int* __restrict__ cnt, int* __restrict__ edges, int E) {
    int e = blockIdx.x * 256 + threadIdx.x;
    if (e < E) {
        int r = recv[e];
        int p = atomicAdd(&cnt[r], 1);
        edges[off[r] + p] = e;
    }
}

// ---------------- aggregate LN(msg) by receiver + build X2 = cat(grid_bf, aggr) ----------------
__global__ void aggregate_kernel(const bf16* __restrict__ T5, const float2* __restrict__ stats,
                                 const float* __restrict__ gw, const float* __restrict__ bw,
                                 const bf16* __restrict__ gridb,
                                 const int* __restrict__ off, const int* __restrict__ edges,
                                 bf16* __restrict__ X2, int G) {
    int g = blockIdx.x * 4 + (threadIdx.x >> 6);
    if (g >= G) return;
    int lane = threadIdx.x & 63;
    int d0 = lane * 8;
    float gg[8], bb[8];
    {
        float4 a = *(const float4*)(gw + d0), b = *(const float4*)(gw + d0 + 4);
        gg[0]=a.x; gg[1]=a.y; gg[2]=a.z; gg[3]=a.w; gg[4]=b.x; gg[5]=b.y; gg[6]=b.z; gg[7]=b.w;
        float4 c = *(const float4*)(bw + d0), d = *(const float4*)(bw + d0 + 4);
        bb[0]=c.x; bb[1]=c.y; bb[2]=c.z; bb[3]=c.w; bb[4]=d.x; bb[5]=d.y; bb[6]=d.z; bb[7]=d.w;
    }
    float s[8] = {0.f, 0.f, 0.f, 0.f, 0.f, 0.f, 0.f, 0.f};
    int a = off[g], b = off[g + 1];
    for (int i = a; i < b; i++) {
        int e = edges[i];
        float2 st = stats[e];
        short8 m = *(const short8*)(T5 + (size_t)e * 512 + d0);
#pragma unroll
        for (int j = 0; j < 8; j++)
            s[j] += (bf2f(m[j]) - st.x) * st.y * gg[j] + bb[j];
    }
    *(short8*)(X2 + (size_t)g * 1024 + d0) = *(const short8*)(gridb + (size_t)g * 512 + d0);
    short8 o;
#pragma unroll
    for (int j = 0; j < 8; j++) o[j] = f2bf(s[j]);
    *(short8*)(X2 + (size_t)g * 1024 + 512 + d0) = o;
}

extern "C" void kernel_launch(void* const* d_in, const int* in_sizes, int n_in,
                              void* d_out, int out_size, void* d_ws, size_t ws_size,
                              hipStream_t stream) {
    const int NM = 2562, NG = 16384, NE = 49152;
    const float* mesh   = (const float*)d_in[0];
    const float* grid   = (const float*)d_in[1];
    const float* attr   = (const float*)d_in[2];
    const int*   eidx   = (const int*)d_in[3];
    const int*   send   = eidx;
    const int*   recv   = eidx + NE;
    const float* emlp_w1 = (const float*)d_in[4];
    const float* emlp_b1 = (const float*)d_in[5];
    const float* emlp_w2 = (const float*)d_in[6];
    const float* emlp_b2 = (const float*)d_in[7];
    const float* emlp_g  = (const float*)d_in[8];
    const float* emlp_be = (const float*)d_in[9];
    const float* ge_w1 = (const float*)d_in[10];
    const float* ge_b1 = (const float*)d_in[11];
    const float* ge_w2 = (const float*)d_in[12];
    const float* ge_b2 = (const float*)d_in[13];
    const float* ge_g  = (const float*)d_in[14];
    const float* ge_be = (const float*)d_in[15];
    const float* gn_w1 = (const float*)d_in[16];
    const float* gn_b1 = (const float*)d_in[17];
    const float* gn_w2 = (const float*)d_in[18];
    const float* gn_b2 = (const float*)d_in[19];
    const float* gn_g  = (const float*)d_in[20];
    const float* gn_be = (const float*)d_in[21];
    const float* fin_w1 = (const float*)d_in[22];
    const float* fin_b1 = (const float*)d_in[23];
    const float* fin_w2 = (const float*)d_in[24];
    const float* fin_b2 = (const float*)d_in[25];
    const float* fin_g  = (const float*)d_in[26];
    const float* fin_be = (const float*)d_in[27];

    char* p = (char*)d_ws;
    auto take = [&](size_t bytes) -> char* {
        char* r = p;
        p += (bytes + 255) & ~(size_t)255;
        return r;
    };
    bf16* emlp_w2T = (bf16*)take((size_t)512 * 512 * 2);
    bf16* geA_T    = (bf16*)take((size_t)512 * 512 * 2);
    bf16* geB_T    = (bf16*)take((size_t)512 * 512 * 2);
    bf16* geC_T    = (bf16*)take((size_t)512 * 512 * 2);
    bf16* ge_w2T   = (bf16*)take((size_t)512 * 512 * 2);
    bf16* gn_w1T   = (bf16*)take((size_t)512 * 1024 * 2);
    bf16* gn_w2T   = (bf16*)take((size_t)512 * 512 * 2);
    bf16* fin_w1T  = (bf16*)take((size_t)512 * 512 * 2);
    bf16* fin_w2T  = (bf16*)take((size_t)128 * 512 * 2);
    bf16* grid_bf  = (bf16*)take((size_t)NG * 512 * 2);
    bf16* mesh_bf  = (bf16*)take((size_t)NM * 512 * 2);
    bf16* bufA     = (bf16*)take((size_t)NE * 512 * 2);  // H1 -> H2 -> X2 -> latent
    bf16* bufB     = (bf16*)take((size_t)NE * 512 * 2);  // T2/edges_emb -> T5 -> T8 -> T11
    bf16* bufC     = (bf16*)take((size_t)NG * 512 * 2);  // grid_proj -> H3 -> H4
    bf16* bufD     = (bf16*)take((size_t)NM * 512 * 2);  // mesh_proj
    float2* stats  = (float2*)take((size_t)NE * 8);
    int*  deg      = (int*)take((size_t)NG * 4);
    int*  cnt      = (int*)take((size_t)NG * 4);
    int*  csr_off  = (int*)take((size_t)(NG + 1) * 4);
    int*  csr_edge = (int*)take((size_t)NE * 4);

    // 1) transpose + bf16-convert all GEMM weights
    TDescs td;
    td.d[0] = {emlp_w2, emlp_w2T, 512, 512, 0};
    td.d[1] = {ge_w1,   geA_T,    512, 512, 0};
    td.d[2] = {ge_w1,   geB_T,    512, 512, 512};
    td.d[3] = {ge_w1,   geC_T,    512, 512, 1024};
    td.d[4] = {ge_w2,   ge_w2T,   512, 512, 0};
    td.d[5] = {gn_w1,   gn_w1T,  1024, 512, 0};
    td.d[6] = {gn_w2,   gn_w2T,   512, 512, 0};
    td.d[7] = {fin_w1,  fin_w1T,  512, 512, 0};
    td.d[8] = {fin_w2,  fin_w2T,  512, 128, 0};
    hipLaunchKernelGGL(transpose_all_kernel, dim3(32, 16, 9), dim3(256), 0, stream, td);

    // 2) bf16 inputs + CSR build (independent of MLP pipeline)
    hipLaunchKernelGGL(cvt_bf16_kernel, dim3((NG * 512 / 4 + 255) / 256), dim3(256), 0, stream,
                       grid, grid_bf, NG * 512);
    hipLaunchKernelGGL(cvt_bf16_kernel, dim3((NM * 512 / 4 + 255) / 256), dim3(256), 0, stream,
                       mesh, mesh_bf, NM * 512);
    hipMemsetAsync(deg, 0, (size_t)NG * 4, stream);
    hipMemsetAsync(cnt, 0, (size_t)NG * 4, stream);
    hipLaunchKernelGGL(degree_kernel, dim3((NE + 255) / 256), dim3(256), 0, stream, recv, deg, NE);
    hipLaunchKernelGGL(scan_kernel, dim3(1), dim3(1024), 0, stream, deg, csr_off);
    hipLaunchKernelGGL(scatter_kernel, dim3((NE + 255) / 256), dim3(256), 0, stream,
                       recv, csr_off, cnt, csr_edge, NE);

    // 3) edge MLP layer1: H1 = relu(attr @ emlp_w1 + b1) -> bufA (wave per row)
    hipLaunchKernelGGL(edge_l1_kernel, dim3(NE / 4), dim3(256), 0, stream,
                       attr, emlp_w1, emlp_b1, bufA, NE);
    // 4) T2 = H1 @ emlp_w2 + b2 -> bufB
    hipLaunchKernelGGL(gemm_bt_kernel<1>, dim3(4, NE / 128), dim3(256), 0, stream,
                       bufA, emlp_w2T, emlp_b2, bufB, NE, 512, 512,
                       (const bf16*)nullptr, (const bf16*)nullptr, (const int*)nullptr, (const int*)nullptr);
    // 5) edges_emb = LN(T2)*g+b (in place, bufB)
    hipLaunchKernelGGL((ln_kernel<0, 512>), dim3(NE / 4), dim3(256), 0, stream,
                       bufB, emlp_g, emlp_be, bufB, (float*)nullptr, (const bf16*)nullptr, NE);

    // 6) grid_proj = grid_bf @ ge_w1[0:512] -> bufC
    hipLaunchKernelGGL(gemm_bt_kernel<0>, dim3(4, NG / 128), dim3(256), 0, stream,
                       grid_bf, geA_T, (const float*)nullptr, bufC, NG, 512, 512,
                       (const bf16*)nullptr, (const bf16*)nullptr, (const int*)nullptr, (const int*)nullptr);
    // 7) mesh_proj = mesh_bf @ ge_w1[512:1024] -> bufD
    hipLaunchKernelGGL(gemm_bt_kernel<0>, dim3(4, (NM + 127) / 128), dim3(256), 0, stream,
                       mesh_bf, geB_T, (const float*)nullptr, bufD, NM, 512, 512,
                       (const bf16*)nullptr, (const bf16*)nullptr, (const int*)nullptr, (const int*)nullptr);
    // 8+9) H2 = relu(edges_emb @ ge_w1[1024:1536] + grid_proj[recv] + mesh_proj[send] + ge_b1)
    //      fused in GEMM epilogue (EPI=3) -> bufA
    hipLaunchKernelGGL(gemm_bt_kernel<3>, dim3(4, NE / 128), dim3(256), 0, stream,
                       bufB, geC_T, ge_b1, bufA, NE, 512, 512,
                       bufC, bufD, send, recv);
    // 10) T5 = H2 @ ge_w2 + b2 -> bufB
    hipLaunchKernelGGL(gemm_bt_kernel<1>, dim3(4, NE / 128), dim3(256), 0, stream,
                       bufA, ge_w2T, ge_b2, bufB, NE, 512, 512,
                       (const bf16*)nullptr, (const bf16*)nullptr, (const int*)nullptr, (const int*)nullptr);
    // 11) msg LN stats only (mu, rs per edge row)
    hipLaunchKernelGGL(ln_stats_kernel, dim3(NE / 4), dim3(256), 0, stream, bufB, stats, NE);
    // 12) X2 = cat(grid_bf, segment_sum(LN(T5))) -> bufA (CSR gather, affine on the fly)
    hipLaunchKernelGGL(aggregate_kernel, dim3(NG / 4), dim3(256), 0, stream,
                       bufB, stats, ge_g, ge_be, grid_bf, csr_off, csr_edge, bufA, NG);

    // 13) H3 = relu(X2 @ gn_w1 + b1) -> bufC
    hipLaunchKernelGGL(gemm_bt_kernel<2>, dim3(4, NG / 128), dim3(256), 0, stream,
                       bufA, gn_w1T, gn_b1, bufC, NG, 512, 1024,
                       (const bf16*)nullptr, (const bf16*)nullptr, (const int*)nullptr, (const int*)nullptr);
    // 14) T8 = H3 @ gn_w2 + b2 -> bufB
    hipLaunchKernelGGL(gemm_bt_kernel<1>, dim3(4, NG / 128), dim3(256), 0, stream,
                       bufC, gn_w2T, gn_b2, bufB, NG, 512, 512,
                       (const bf16*)nullptr, (const bf16*)nullptr, (const int*)nullptr, (const int*)nullptr);
    // 15) latent = grid_bf + LN(T8)*g+b -> bufA (bf16)
    hipLaunchKernelGGL((ln_kernel<2, 512>), dim3(NG / 4), dim3(256), 0, stream,
                       bufB, gn_g, gn_be, bufA, (float*)nullptr, grid_bf, NG);

    // 16) H4 = relu(latent @ fin_w1 + b1) -> bufC
    hipLaunchKernelGGL(gemm_bt_kernel<2>, dim3(4, NG / 128), dim3(256), 0, stream,
                       bufA, fin_w1T, fin_b1, bufC, NG, 512, 512,
                       (const bf16*)nullptr, (const bf16*)nullptr, (const int*)nullptr, (const int*)nullptr);
    // 17) T11 = H4 @ fin_w2 + b2 -> bufB  [N=128]
    hipLaunchKernelGGL(gemm_bt_kernel<1>, dim3(1, NG / 128), dim3(256), 0, stream,
                       bufC, fin_w2T, fin_b2, bufB, NG, 128, 512,
                       (const bf16*)nullptr, (const bf16*)nullptr, (const int*)nullptr, (const int*)nullptr);
    // 18) out = LN(T11)*g+b -> d_out (f32)
    hipLaunchKernelGGL((ln_kernel<3, 128>), dim3(NG / 4), dim3(256), 0, stream,
                       bufB, fin_g, fin_be, (bf16*)nullptr, (float*)d_out, (const bf16*)nullptr, NG);
}